// Round 5
// baseline (2731.562 us; speedup 1.0000x reference)
//
#include <hip/hip_runtime.h>

// ---------- types ----------
typedef __bf16 bft;
typedef bft bf16x8 __attribute__((ext_vector_type(8)));
typedef bft bf16x4 __attribute__((ext_vector_type(4)));
typedef bft bf16x2 __attribute__((ext_vector_type(2)));
typedef float f32x4 __attribute__((ext_vector_type(4)));
typedef unsigned long long u64;
typedef unsigned int u32;
typedef u32 u32x4 __attribute__((ext_vector_type(4)));

#define LN_EPS 1e-5f
#define SENT 0x7FC17FC1u   // bf16-pair NaN pattern: impossible for |h|<=1 outputs

// B=32, S=256, H=1024, HL=512, E=256, L=5. All big GEMMs have K=1024.

__device__ __forceinline__ float sigmoidf_(float x) {
    return 1.f / (1.f + __expf(-x));
}
__device__ __forceinline__ float tanhf_(float x) {
    float e = __expf(-2.f * fabsf(x));
    float t = (1.f - e) / (1.f + e);
    return copysignf(t, x);
}

// ---------- f32 -> bf16 convert (vector-4) ----------
__global__ void cvt_f32_bf16(const float* __restrict__ in, bft* __restrict__ out, int n4) {
    int i = blockIdx.x * blockDim.x + threadIdx.x;
    if (i < n4) {
        float4 v = ((const float4*)in)[i];
        bf16x4 o = { (bft)v.x, (bft)v.y, (bft)v.z, (bft)v.w };
        ((bf16x4*)out)[i] = o;
    }
}

// ---------- hg init: buf0 = 0 (valid h0), buf1..3 = sentinel ----------
// hg layout: [dir(2)][buf(4)][bat(32)][j2(256)] u32
__global__ void init_hg(u32* __restrict__ hg) {
    int i = blockIdx.x * blockDim.x + threadIdx.x;   // 65536
    int buf = (i >> 13) & 3;
    hg[i] = (buf == 0) ? 0u : SENT;
}

// ---------- mask bit-pack: mask[32][256] int -> mbits[w(8)][batch(32)] u32 ----------
__global__ void pack_mask(const int* __restrict__ mask, u32* __restrict__ mbits) {
    int t = blockIdx.x * blockDim.x + threadIdx.x;
    if (t < 256) {
        int w = t >> 5, b = t & 31;
        u32 v = 0;
        for (int i = 0; i < 32; ++i)
            v |= (mask[b * 256 + w * 32 + i] ? 1u : 0u) << i;
        mbits[w * 32 + b] = v;
    }
}

// ---------- Wih convert with gate-interleave row permutation ----------
// dest row r' = j*4+g  <-  src row g*512+j   (so gin cols become [j][gate])
__global__ __launch_bounds__(256) void cvt_permute_wih(
    const float* __restrict__ in, bft* __restrict__ out)
{
    int r = blockIdx.x;                       // 0..2047 dest row
    int src = (r & 3) * 512 + (r >> 2);
    int t = threadIdx.x;
    float4 v = ((const float4*)(in + (size_t)src * 1024))[t];
    bf16x4 o = { (bft)v.x, (bft)v.y, (bft)v.z, (bft)v.w };
    ((bf16x4*)(out + (size_t)r * 1024))[t] = o;
}

// bias permuted the same way
__global__ void permute_bias(const float* __restrict__ in, float* __restrict__ out) {
    int t = blockIdx.x * blockDim.x + threadIdx.x;
    if (t < 2048) out[t] = in[(t & 3) * 512 + (t >> 2)];
}

// ---------- transpose+convert W1/W2 ([L][K=h][N=d] f32 -> [L][N][K] bf16) ----------
__global__ __launch_bounds__(256) void transpose_cvt_w(
    const float* __restrict__ W1, const float* __restrict__ W2,
    bft* __restrict__ W1t, bft* __restrict__ W2t)
{
    __shared__ float tile[32][33];
    int z = blockIdx.z;
    int l = z >> 1;
    const float* src = ((z & 1) ? W2 : W1) + ((size_t)l << 20);
    bft* dst = ((z & 1) ? W2t : W1t) + ((size_t)l << 20);
    int tx = threadIdx.x & 31, ty = threadIdx.x >> 5;
    int bx = blockIdx.x * 32, by = blockIdx.y * 32;
    for (int r = ty; r < 32; r += 8)
        tile[r][tx] = src[(size_t)(by + r) * 1024 + bx + tx];
    __syncthreads();
    for (int r = ty; r < 32; r += 8)
        dst[(size_t)(bx + r) * 1024 + by + tx] = (bft)tile[tx][r];
}

// ---------- bf16 MFMA GEMM, 128x128 tile, BK=32, 4 waves, B^T ([N][K]) input ----------
// Staging now via global_load_lds width=16 (m97 structure): LDS layout is lane-linear
// (byte offset = c*16), so the wave-uniform-base + lane*16 constraint holds.
// remapLog >= 0: row remap. remapLog < 0: gin mode (bilstm-coalesced layout).
__global__ __launch_bounds__(256) void gemm_bt(
    const bft* __restrict__ A, const bft* __restrict__ Bt,
    const float* __restrict__ bias, const int* __restrict__ langs,
    int langStrideB, int langStrideBias,
    float* __restrict__ outF, bft* __restrict__ outB,
    int remapLog, int remapMul, int ldc)
{
    const int K = 1024;
    int tn = blockIdx.x, tm = blockIdx.y;
    int row0 = tm * 128, col0 = tn * 128;
    int lang = langs ? langs[row0 >> 8] : 0;   // 256 rows per batch elem; 128-tile never crosses b
    const bft* Ap = A + (size_t)row0 * K;
    const bft* Bp = Bt + (size_t)lang * langStrideB + (size_t)col0 * K;
    const float* biasp = bias + (size_t)lang * langStrideBias + col0;

    __shared__ bft As[128 * 32];
    __shared__ bft Bs[128 * 32];

    int t = threadIdx.x;
    int lane = t & 63, wave = t >> 6;
    int wm = wave & 1, wn = wave >> 1;
    int lrow = lane & 15, quad = lane >> 4;

    f32x4 acc[4][4] = {};

    for (int k0 = 0; k0 < K; k0 += 32) {
        __syncthreads();
#pragma unroll
        for (int c0 = 0; c0 < 512; c0 += 256) {    // 512 chunks of 16B, 2 per thread (A and B)
            int c = c0 + t;
            int r = c >> 2, co = (c & 3) << 3;
            __builtin_amdgcn_global_load_lds(
                (const __attribute__((address_space(1))) u32*)(Ap + (size_t)r * K + k0 + co),
                (__attribute__((address_space(3))) u32*)(As + c * 8), 16, 0, 0);
            __builtin_amdgcn_global_load_lds(
                (const __attribute__((address_space(1))) u32*)(Bp + (size_t)r * K + k0 + co),
                (__attribute__((address_space(3))) u32*)(Bs + c * 8), 16, 0, 0);
        }
        __syncthreads();
        bf16x8 af[4], bfr[4];
#pragma unroll
        for (int i = 0; i < 4; ++i)
            af[i] = *(const bf16x8*)(As + (wm * 64 + i * 16 + lrow) * 32 + quad * 8);
#pragma unroll
        for (int j = 0; j < 4; ++j)
            bfr[j] = *(const bf16x8*)(Bs + (wn * 64 + j * 16 + lrow) * 32 + quad * 8);
#pragma unroll
        for (int i = 0; i < 4; ++i)
#pragma unroll
            for (int j = 0; j < 4; ++j)
                acc[i][j] = __builtin_amdgcn_mfma_f32_16x16x32_bf16(af[i], bfr[j], acc[i][j], 0, 0, 0);
    }

#pragma unroll
    for (int i = 0; i < 4; ++i) {
#pragma unroll
        for (int j = 0; j < 4; ++j) {
#pragma unroll
            for (int r = 0; r < 4; ++r) {
                int m = wm * 64 + i * 16 + quad * 4 + r;   // C row = quad*4+reg
                int n = wn * 64 + j * 16 + lrow;           // C col = lane&15
                int grow = row0 + m;
                float v = acc[i][j][r] + biasp[n];
                size_t idx;
                if (remapLog < 0) {
                    // gin layout: [s][gslice(64)][tc(256)*4 + gate]
                    int b = grow >> 8, s = grow & 255;
                    int col = col0 + n;
                    int jj = col >> 2, gg = col & 3;
                    int jp = jj & 7, gs = jj >> 3;
                    int tc = (((b >> 4) * 2 + (jp >> 2)) << 6) + ((jp & 3) << 4) + (b & 15);
                    idx = (((size_t)s * 64 + gs) << 10) + (tc << 2) + gg;
                } else {
                    int orow = remapLog ? ((grow & ((1 << remapLog) - 1)) * remapMul + (grow >> remapLog))
                                        : grow;
                    idx = (size_t)orow * ldc + col0 + n;
                }
                if (outF) outF[idx] = v;
                else outB[idx] = (bft)v;
            }
        }
    }
}

// ---------- LayerNorm + ReLU per row, f32 in -> bf16 out ----------
__global__ __launch_bounds__(256) void ln_relu_kernel(
    const float* __restrict__ h1, bft* __restrict__ a2,
    const float* __restrict__ ln_g, const float* __restrict__ ln_b,
    const int* __restrict__ langs)
{
    int row = blockIdx.x;
    int lang = langs[row >> 8];
    const float* x = h1 + (size_t)row * 1024;
    int t = threadIdx.x;
    float4 v = ((const float4*)x)[t];
    float s = v.x + v.y + v.z + v.w;
    float ss = v.x * v.x + v.y * v.y + v.z * v.z + v.w * v.w;
#pragma unroll
    for (int off = 32; off > 0; off >>= 1) {
        s += __shfl_down(s, off, 64);
        ss += __shfl_down(ss, off, 64);
    }
    __shared__ float red[8];
    int wave = t >> 6, lane = t & 63;
    if (lane == 0) { red[wave] = s; red[4 + wave] = ss; }
    __syncthreads();
    float S = red[0] + red[1] + red[2] + red[3];
    float SS = red[4] + red[5] + red[6] + red[7];
    float mean = S * (1.f / 1024.f);
    float var = SS * (1.f / 1024.f) - mean * mean;   // population var (ddof=0)
    float inv = rsqrtf(var + LN_EPS);
    float4 g = ((const float4*)(ln_g + (size_t)lang * 1024))[t];
    float4 b = ((const float4*)(ln_b + (size_t)lang * 1024))[t];
    float y0 = fmaxf(0.f, (v.x - mean) * inv * g.x + b.x);
    float y1 = fmaxf(0.f, (v.y - mean) * inv * g.y + b.y);
    float y2 = fmaxf(0.f, (v.z - mean) * inv * g.z + b.z);
    float y3 = fmaxf(0.f, (v.w - mean) * inv * g.w + b.w);
    bf16x4 o = { (bft)y0, (bft)y1, (bft)y2, (bft)y3 };
    ((bf16x4*)(a2 + (size_t)row * 1024))[t] = o;
}

// ---------- BiLSTM recurrence: barrier-free, LDS-free, direct-fragment exchange ----------
// 128 WGs (64/dir, 8 h-cols each), but each WAVE free-runs — ZERO __syncthreads in loop.
//  - h exchange layout [dir][buf(4)][bat(32)][j2(256)] u32 (bf16 pairs): each lane
//    direct-loads its 16 MFMA B-fragments (dwordx4, full-line coalesced across a wave)
//    from LLC with per-fragment sentinel validation. No LDS staging at all.
//  - per-frag re-poll with s_sleep backoff; wave-uniform exit via __ballot.
//  - rotation clear of buf[(it+2)&3] (own words) is drained by the poll's vmcnt(0)
//    before this wave's next publish -> clear always precedes step-(it+2) publishes
//    (transitively ordered through the observation chain). All waves stay within 2 steps.
//  - dir/gslice from blockIdx so each direction clusters on half the XCDs (hint only).
// gin_*: [S][gslice][1024] bf16 pre-swizzled. ys: [S][B][1024] bf16, fire-and-forget.
__global__ __launch_bounds__(256) void bilstm_kernel(
    const bft* __restrict__ gin_f, const bft* __restrict__ gin_b,
    const bft* __restrict__ Whh_f, const bft* __restrict__ Whh_b,
    const u32* __restrict__ mbits, bft* __restrict__ ys,
    u32* __restrict__ hg)
{
    int blk = blockIdx.x;
    int dir = (blk & 7) >> 2;                 // XCD-clustered: f on XCD 0-3, b on 4-7
    int gslice = ((blk >> 3) << 2) + (blk & 3);
    const bft* Whh = dir ? Whh_b : Whh_f;
    const bft* gin = dir ? gin_b : gin_f;
    u32* hbase = hg + (size_t)dir * 4 * 8192;

    int t = threadIdx.x;
    int lane = t & 63, wave = t >> 6;
    int wm = wave & 1, wn = wave >> 1;
    int lrow = lane & 15, quad = lane >> 4;

    // ---- loop-invariant Whh fragments -> registers (A-operand, rows interleaved j*4+g) ----
    bf16x8 wf[16];
    {
        int row32 = wm * 16 + lrow;            // local A-row
        int jl = row32 >> 2, g = row32 & 3;
        const bft* wp = Whh + (size_t)(g * 512 + (gslice << 3) + jl) * 512 + quad * 8;
#pragma unroll
        for (int kk = 0; kk < 16; ++kk)
            wf[kk] = *(const bf16x8*)(wp + kk * 32);
    }

    int batch = wn * 16 + lrow;         // this lane's output batch (C col; also B-frag row)
    int fbase = batch * 256 + quad * 4; // u32 base of this lane's frag column in a buffer
    int pword = batch * 256 + (gslice << 2) + wm * 2 + (quad >> 1);  // publish word (even quads)
    u32* ysU = (u32*)ys;
    float cs = 0.f, hp = 0.f;           // cell / hidden state, 1 cell per lane
    u32 mw = 0;

    for (int it = 0; it < 256; ++it) {
        int tt = dir ? (255 - it) : it;

        // ---- coalesced gin prefetch: lane t reads its own 4 gates (8B) ----
        bf16x4 gv = *(const bf16x4*)(gin + ((((size_t)tt * 64 + gslice) << 10) + (t << 2)));
        if ((it & 31) == 0) mw = mbits[(tt >> 5) * 32 + batch];
        int mk = (mw >> (tt & 31)) & 1;

        // ---- rotation clear: own word of buf[(it+2)&3] -> sentinel (fire & forget) ----
        if (!(lane & 16)) {
            u32* ca = hbase + (size_t)((it + 2) & 3) * 8192 + pword;
            u32 sv = SENT;
            asm volatile("global_store_dword %0, %1, off sc0 sc1" :: "v"(ca), "v"(sv) : "memory");
        }

        // ---- poll + direct-load the 16 B-fragments of buf[it&3] (self-validating) ----
        const u32* hq = hbase + (size_t)(it & 3) * 8192 + fbase;
        u32x4 r[16];
        u32 need = 0xffffu;
        for (;;) {
#pragma unroll
            for (int i = 0; i < 16; ++i)
                if (need & (1u << i))
                    asm volatile("global_load_dwordx4 %0, %1, off sc0 sc1"
                                 : "=v"(r[i]) : "v"(hq + i * 16) : "memory");
            asm volatile("s_waitcnt vmcnt(0)" ::: "memory");
#pragma unroll
            for (int i = 0; i < 16; ++i)
                if ((need & (1u << i)) &&
                    r[i][0] != SENT && r[i][1] != SENT && r[i][2] != SENT && r[i][3] != SENT)
                    need &= ~(1u << i);
            if (!__ballot(need)) break;      // wave-uniform exit
            __builtin_amdgcn_s_sleep(1);     // backoff: bounds retry traffic
        }

        // ---- gates^T = Whh_slice @ h^T : lane -> (i,f,g,o) of one (j,batch) cell ----
        f32x4 acc0 = {}, acc1 = {};
#pragma unroll
        for (int kk = 0; kk < 16; ++kk) {
            union { u32x4 u; bf16x8 h; } ub; ub.u = r[kk];
            if (kk & 1) acc1 = __builtin_amdgcn_mfma_f32_16x16x32_bf16(wf[kk], ub.h, acc1, 0, 0, 0);
            else        acc0 = __builtin_amdgcn_mfma_f32_16x16x32_bf16(wf[kk], ub.h, acc0, 0, 0, 0);
        }
        f32x4 acc = acc0 + acc1;

        // ---- activation: 1 cell per lane, fully register-local ----
        float xi = acc[0] + (float)gv[0];
        float xf = acc[1] + (float)gv[1];
        float xg = acc[2] + (float)gv[2];
        float xo = acc[3] + (float)gv[3];
        float cn = sigmoidf_(xf) * cs + sigmoidf_(xi) * tanhf_(xg);
        float hn = sigmoidf_(xo) * tanhf_(cn);
        if (mk) { cs = cn; hp = hn; }
        union { bft h; unsigned short u; } hc; hc.h = (bft)hp;
        u32 own = (u32)hc.u | ((mk ? (u32)hc.u : 0u) << 16);   // low: h16, high: y16
        u32 par = __shfl_xor(own, 16, 64);                     // partner = quad^1 (j +/- 1)
        u32 hpair = (own & 0xffffu) | (par << 16);             // (h[j], h[j+1]) on even quads
        u32 ypair = (own >> 16) | (par & 0xffff0000u);         // (y[j], y[j+1]) on even quads

        if (!(lane & 16)) {                                    // fire-and-forget h publish
            u32* ha = hbase + (size_t)((it + 1) & 3) * 8192 + pword;
            asm volatile("global_store_dword %0, %1, off sc0 sc1" :: "v"(ha), "v"(hpair) : "memory");
            // ys store — off the critical path
            ysU[((size_t)tt * 32 + batch) * 512 + dir * 256
                + (gslice << 2) + wm * 2 + (quad >> 1)] = ypair;
        }
    }
}

// ---------- host launcher ----------
extern "C" void kernel_launch(void* const* d_in, const int* in_sizes, int n_in,
                              void* d_out, int out_size, void* d_ws, size_t ws_size,
                              hipStream_t stream)
{
    const float* X     = (const float*)d_in[0];   // [32,256,1024]
    const int*   amask = (const int*)d_in[1];     // [32,256]
    const int*   langs = (const int*)d_in[2];     // [32]
    const float* W1    = (const float*)d_in[3];   // [5,1024,1024] (K-major)
    const float* b1    = (const float*)d_in[4];   // [5,1024]
    const float* ln_g  = (const float*)d_in[5];
    const float* ln_b  = (const float*)d_in[6];
    const float* W2    = (const float*)d_in[7];
    const float* b2    = (const float*)d_in[8];
    const float* Wih_f = (const float*)d_in[9];   // [2048,1024] = [N][K]
    const float* Whh_f = (const float*)d_in[10];  // [2048,512]
    const float* b_f   = (const float*)d_in[11];  // [2048]
    const float* Wih_b = (const float*)d_in[12];
    const float* Whh_b = (const float*)d_in[13];
    const float* b_b   = (const float*)d_in[14];
    const float* Wp    = (const float*)d_in[15];  // [256,1024] = [N][K]
    const float* bp    = (const float*)d_in[16];
    float* out = (float*)d_out;

    char* ws = (char*)d_ws;
    size_t off = 0;
    auto alloc = [&](size_t bytes) -> void* {
        void* p = ws + off;
        off += (bytes + 255) & ~(size_t)255;
        return p;
    };
    bft* Xbf   = (bft*)alloc(8192ull * 1024 * 2);
    bft* W1t   = (bft*)alloc(5ull * 1024 * 1024 * 2);
    bft* W2t   = (bft*)alloc(5ull * 1024 * 1024 * 2);
    bft* Wihf  = (bft*)alloc(2048ull * 1024 * 2);
    bft* Wihb  = (bft*)alloc(2048ull * 1024 * 2);
    bft* Whhf  = (bft*)alloc(2048ull * 512 * 2);
    bft* Whhb  = (bft*)alloc(2048ull * 512 * 2);
    bft* Wpb   = (bft*)alloc(256ull * 1024 * 2);
    float* h1  = (float*)alloc(8192ull * 1024 * 4);
    bft* a2    = (bft*)alloc(8192ull * 1024 * 2);
    bft* adapt = (bft*)alloc(8192ull * 1024 * 2);
    bft* ginf  = (bft*)alloc(256ull * 32 * 2048 * 2);
    bft* ginb  = (bft*)alloc(256ull * 32 * 2048 * 2);
    bft* ysb   = (bft*)alloc(256ull * 32 * 1024 * 2);
    float* pbf = (float*)alloc(2048ull * 4);             // permuted b_f
    float* pbb = (float*)alloc(2048ull * 4);             // permuted b_b
    u32* hg    = (u32*)alloc(2ull * 4 * 8192 * 4);       // [dir][4 bufs][bat][j2], 256 KB
    u32* mbits = (u32*)alloc(256ull * 4);                // packed mask bits
    (void)ws_size; (void)in_sizes; (void)n_in; (void)out_size;

    auto cvt = [&](const float* src, bft* dst, int n) {
        int n4 = n >> 2;
        hipLaunchKernelGGL(cvt_f32_bf16, dim3((n4 + 255) / 256), dim3(256), 0, stream, src, dst, n4);
    };
    cvt(X, Xbf, 8192 * 1024);
    hipLaunchKernelGGL(cvt_permute_wih, dim3(2048), dim3(256), 0, stream, Wih_f, Wihf);
    hipLaunchKernelGGL(cvt_permute_wih, dim3(2048), dim3(256), 0, stream, Wih_b, Wihb);
    cvt(Whh_f, Whhf, 2048 * 512);
    cvt(Whh_b, Whhb, 2048 * 512);
    cvt(Wp, Wpb, 256 * 1024);
    hipLaunchKernelGGL(permute_bias, dim3(8), dim3(256), 0, stream, b_f, pbf);
    hipLaunchKernelGGL(permute_bias, dim3(8), dim3(256), 0, stream, b_b, pbb);
    hipLaunchKernelGGL(init_hg, dim3(256), dim3(256), 0, stream, hg);
    hipLaunchKernelGGL(pack_mask, dim3(1), dim3(256), 0, stream, amask, mbits);
    hipLaunchKernelGGL(transpose_cvt_w, dim3(32, 32, 10), dim3(256), 0, stream, W1, W2, W1t, W2t);

    // Adapter GEMM1: h1 = X @ W1[lang] + b1[lang]   (f32 out for LN)
    hipLaunchKernelGGL(gemm_bt, dim3(8, 64), dim3(256), 0, stream,
        Xbf, W1t, b1, langs, 1024 * 1024, 1024, h1, (bft*)nullptr, 0, 0, 1024);
    // LN + ReLU -> a2 (bf16)
    hipLaunchKernelGGL(ln_relu_kernel, dim3(8192), dim3(256), 0, stream, h1, a2, ln_g, ln_b, langs);
    // Adapter GEMM2: adapt = a2 @ W2[lang] + b2[lang]   (bf16 out)
    hipLaunchKernelGGL(gemm_bt, dim3(8, 64), dim3(256), 0, stream,
        a2, W2t, b2, langs, 1024 * 1024, 1024, (float*)nullptr, adapt, 0, 0, 1024);
    // Input gates (gate-interleaved cols, bilstm-coalesced layout): remapLog = -1
    hipLaunchKernelGGL(gemm_bt, dim3(16, 64), dim3(256), 0, stream,
        adapt, Wihf, pbf, (const int*)nullptr, 0, 0, (float*)nullptr, ginf, -1, 0, 0);
    hipLaunchKernelGGL(gemm_bt, dim3(16, 64), dim3(256), 0, stream,
        adapt, Wihb, pbb, (const int*)nullptr, 0, 0, (float*)nullptr, ginb, -1, 0, 0);
    // Recurrence (cooperative launch guarantees co-residency for the spin-wait)
    {
        void* args[] = { (void*)&ginf, (void*)&ginb, (void*)&Whhf, (void*)&Whhb,
                         (void*)&mbits, (void*)&ysb, (void*)&hg };
        hipLaunchCooperativeKernel((const void*)bilstm_kernel, dim3(128), dim3(256), args, 0, stream);
    }
    // Projection: out = ys @ Wp^T + bp, remap row (s*32+b) -> (b*256+s), ldc 256
    hipLaunchKernelGGL(gemm_bt, dim3(2, 64), dim3(256), 0, stream,
        ysb, Wpb, bp, (const int*)nullptr, 0, 0, out, (bft*)nullptr, 5, 256, 256);
}

// Round 6
// 1693.266 us; speedup vs baseline: 1.6132x; 1.6132x over previous
//
#include <hip/hip_runtime.h>

// ---------- types ----------
typedef __bf16 bft;
typedef bft bf16x8 __attribute__((ext_vector_type(8)));
typedef bft bf16x4 __attribute__((ext_vector_type(4)));
typedef bft bf16x2 __attribute__((ext_vector_type(2)));
typedef float f32x4 __attribute__((ext_vector_type(4)));
typedef unsigned long long u64;
typedef unsigned int u32;
typedef u32 u32x4 __attribute__((ext_vector_type(4)));

#define LN_EPS 1e-5f
#define SENT  0x7FC17FC1u   // bf16-pair NaN pattern: impossible for |h|<=1 outputs
#define MAGIC 0xA5A5A5A5u

// B=32, S=256, H=1024, HL=512, E=256, L=5. All big GEMMs have K=1024.

__device__ __forceinline__ float sigmoidf_(float x) {
    return 1.f / (1.f + __expf(-x));
}
__device__ __forceinline__ float tanhf_(float x) {
    float e = __expf(-2.f * fabsf(x));
    float t = (1.f - e) / (1.f + e);
    return copysignf(t, x);
}

// ---------- f32 -> bf16 convert (vector-4) ----------
__global__ void cvt_f32_bf16(const float* __restrict__ in, bft* __restrict__ out, int n4) {
    int i = blockIdx.x * blockDim.x + threadIdx.x;
    if (i < n4) {
        float4 v = ((const float4*)in)[i];
        bf16x4 o = { (bft)v.x, (bft)v.y, (bft)v.z, (bft)v.w };
        ((bf16x4*)out)[i] = o;
    }
}

__global__ void zero_u32(u32* __restrict__ p, int n) {
    int i = blockIdx.x * blockDim.x + threadIdx.x;
    if (i < n) p[i] = 0u;
}

// ---------- hg init: buf0 = 0 (valid h0), buf1..3 = sentinel ----------
// hg layout: [dir(2)][buf(4)][gs(32)][bat(32)][jw(8)] u32
__global__ void init_hg(u32* __restrict__ hg) {
    int i = blockIdx.x * blockDim.x + threadIdx.x;   // 65536
    int buf = (i >> 13) & 3;
    hg[i] = (buf == 0) ? 0u : SENT;
}

// ---------- mask bit-pack: mask[32][256] int -> mbits[w(8)][batch(32)] u32 ----------
__global__ void pack_mask(const int* __restrict__ mask, u32* __restrict__ mbits) {
    int t = blockIdx.x * blockDim.x + threadIdx.x;
    if (t < 256) {
        int w = t >> 5, b = t & 31;
        u32 v = 0;
        for (int i = 0; i < 32; ++i)
            v |= (mask[b * 256 + w * 32 + i] ? 1u : 0u) << i;
        mbits[w * 32 + b] = v;
    }
}

// ---------- Wih convert with gate-interleave row permutation ----------
// dest row r' = j*4+g  <-  src row g*512+j
__global__ __launch_bounds__(256) void cvt_permute_wih(
    const float* __restrict__ in, bft* __restrict__ out)
{
    int r = blockIdx.x;                       // 0..2047 dest row
    int src = (r & 3) * 512 + (r >> 2);
    int t = threadIdx.x;
    float4 v = ((const float4*)(in + (size_t)src * 1024))[t];
    bf16x4 o = { (bft)v.x, (bft)v.y, (bft)v.z, (bft)v.w };
    ((bf16x4*)(out + (size_t)r * 1024))[t] = o;
}

__global__ void permute_bias(const float* __restrict__ in, float* __restrict__ out) {
    int t = blockIdx.x * blockDim.x + threadIdx.x;
    if (t < 2048) out[t] = in[(t & 3) * 512 + (t >> 2)];
}

// ---------- transpose+convert W1/W2 ([L][K=h][N=d] f32 -> [L][N][K] bf16) ----------
__global__ __launch_bounds__(256) void transpose_cvt_w(
    const float* __restrict__ W1, const float* __restrict__ W2,
    bft* __restrict__ W1t, bft* __restrict__ W2t)
{
    __shared__ float tile[32][33];
    int z = blockIdx.z;
    int l = z >> 1;
    const float* src = ((z & 1) ? W2 : W1) + ((size_t)l << 20);
    bft* dst = ((z & 1) ? W2t : W1t) + ((size_t)l << 20);
    int tx = threadIdx.x & 31, ty = threadIdx.x >> 5;
    int bx = blockIdx.x * 32, by = blockIdx.y * 32;
    for (int r = ty; r < 32; r += 8)
        tile[r][tx] = src[(size_t)(by + r) * 1024 + bx + tx];
    __syncthreads();
    for (int r = ty; r < 32; r += 8)
        dst[(size_t)(bx + r) * 1024 + by + tx] = (bft)tile[tx][r];
}

// ---------- bf16 MFMA GEMM, 128x128 tile, BK=32, 4 waves, global_load_lds staging ----------
// remapLog >= 0: row remap. remapLog < 0: gin mode (bilstm-coalesced, 32 gslices).
__global__ __launch_bounds__(256) void gemm_bt(
    const bft* __restrict__ A, const bft* __restrict__ Bt,
    const float* __restrict__ bias, const int* __restrict__ langs,
    int langStrideB, int langStrideBias,
    float* __restrict__ outF, bft* __restrict__ outB,
    int remapLog, int remapMul, int ldc)
{
    const int K = 1024;
    int tn = blockIdx.x, tm = blockIdx.y;
    int row0 = tm * 128, col0 = tn * 128;
    int lang = langs ? langs[row0 >> 8] : 0;
    const bft* Ap = A + (size_t)row0 * K;
    const bft* Bp = Bt + (size_t)lang * langStrideB + (size_t)col0 * K;
    const float* biasp = bias + (size_t)lang * langStrideBias + col0;

    __shared__ bft As[128 * 32];
    __shared__ bft Bs[128 * 32];

    int t = threadIdx.x;
    int lane = t & 63, wave = t >> 6;
    int wm = wave & 1, wn = wave >> 1;
    int lrow = lane & 15, quad = lane >> 4;

    f32x4 acc[4][4] = {};

    for (int k0 = 0; k0 < K; k0 += 32) {
        __syncthreads();
#pragma unroll
        for (int c0 = 0; c0 < 512; c0 += 256) {
            int c = c0 + t;
            int r = c >> 2, co = (c & 3) << 3;
            __builtin_amdgcn_global_load_lds(
                (const __attribute__((address_space(1))) u32*)(Ap + (size_t)r * K + k0 + co),
                (__attribute__((address_space(3))) u32*)(As + c * 8), 16, 0, 0);
            __builtin_amdgcn_global_load_lds(
                (const __attribute__((address_space(1))) u32*)(Bp + (size_t)r * K + k0 + co),
                (__attribute__((address_space(3))) u32*)(Bs + c * 8), 16, 0, 0);
        }
        __syncthreads();
        bf16x8 af[4], bfr[4];
#pragma unroll
        for (int i = 0; i < 4; ++i)
            af[i] = *(const bf16x8*)(As + (wm * 64 + i * 16 + lrow) * 32 + quad * 8);
#pragma unroll
        for (int j = 0; j < 4; ++j)
            bfr[j] = *(const bf16x8*)(Bs + (wn * 64 + j * 16 + lrow) * 32 + quad * 8);
#pragma unroll
        for (int i = 0; i < 4; ++i)
#pragma unroll
            for (int j = 0; j < 4; ++j)
                acc[i][j] = __builtin_amdgcn_mfma_f32_16x16x32_bf16(af[i], bfr[j], acc[i][j], 0, 0, 0);
    }

#pragma unroll
    for (int i = 0; i < 4; ++i) {
#pragma unroll
        for (int j = 0; j < 4; ++j) {
#pragma unroll
            for (int r = 0; r < 4; ++r) {
                int m = wm * 64 + i * 16 + quad * 4 + r;
                int n = wn * 64 + j * 16 + lrow;
                int grow = row0 + m;
                float v = acc[i][j][r] + biasp[n];
                size_t idx;
                if (remapLog < 0) {
                    // gin layout: [s][gs(32)][lane(256)*8 + e]; lane = w*64+quad*16+(b&15),
                    // e = (b>>4)*4 + gate  (cell j = gs*16 + w*4 + quad)
                    int b = grow >> 8, s = grow & 255;
                    int col = col0 + n;
                    int jj = col >> 2, gg = col & 3;
                    int gs = jj >> 4, jl = jj & 15;
                    int ln = (jl >> 2) * 64 + (jl & 3) * 16 + (b & 15);
                    int e = ((b >> 4) << 2) + gg;
                    idx = (((size_t)s * 32 + gs) << 11) + ln * 8 + e;
                } else {
                    int orow = remapLog ? ((grow & ((1 << remapLog) - 1)) * remapMul + (grow >> remapLog))
                                        : grow;
                    idx = (size_t)orow * ldc + col0 + n;
                }
                if (outF) outF[idx] = v;
                else outB[idx] = (bft)v;
            }
        }
    }
}

// ---------- LayerNorm + ReLU per row, f32 in -> bf16 out ----------
__global__ __launch_bounds__(256) void ln_relu_kernel(
    const float* __restrict__ h1, bft* __restrict__ a2,
    const float* __restrict__ ln_g, const float* __restrict__ ln_b,
    const int* __restrict__ langs)
{
    int row = blockIdx.x;
    int lang = langs[row >> 8];
    const float* x = h1 + (size_t)row * 1024;
    int t = threadIdx.x;
    float4 v = ((const float4*)x)[t];
    float s = v.x + v.y + v.z + v.w;
    float ss = v.x * v.x + v.y * v.y + v.z * v.z + v.w * v.w;
#pragma unroll
    for (int off = 32; off > 0; off >>= 1) {
        s += __shfl_down(s, off, 64);
        ss += __shfl_down(ss, off, 64);
    }
    __shared__ float red[8];
    int wave = t >> 6, lane = t & 63;
    if (lane == 0) { red[wave] = s; red[4 + wave] = ss; }
    __syncthreads();
    float S = red[0] + red[1] + red[2] + red[3];
    float SS = red[4] + red[5] + red[6] + red[7];
    float mean = S * (1.f / 1024.f);
    float var = SS * (1.f / 1024.f) - mean * mean;
    float inv = rsqrtf(var + LN_EPS);
    float4 g = ((const float4*)(ln_g + (size_t)lang * 1024))[t];
    float4 b = ((const float4*)(ln_b + (size_t)lang * 1024))[t];
    float y0 = fmaxf(0.f, (v.x - mean) * inv * g.x + b.x);
    float y1 = fmaxf(0.f, (v.y - mean) * inv * g.y + b.y);
    float y2 = fmaxf(0.f, (v.z - mean) * inv * g.z + b.z);
    float y3 = fmaxf(0.f, (v.w - mean) * inv * g.w + b.w);
    bf16x4 o = { (bft)y0, (bft)y1, (bft)y2, (bft)y3 };
    ((bf16x4*)(a2 + (size_t)row * 1024))[t] = o;
}

// ---------- BiLSTM recurrence ----------
// 32 WGs/dir x 16 h-cols. dir = blk&7 (0/1) -> under round-robin blk%8->XCD mapping each
// dir's 32 WGs land on ONE XCD (1 WG/CU) -> h exchange is L2-coherent (plain write-through
// stores + sc0 L1-bypass loads) at ~200cyc instead of LLC ~700. Placement is VERIFIED by a
// startup probe (sc0 store+poll w/ timeout) + LLC consensus vote; on failure falls back to
// sc0 sc1 (LLC) ops — identical protocol, placement-independent.
// Sentinel protocol (R4, proven): 4 rotating buffers, data self-validating (!= SENT),
// fire-and-forget publishes, rotation clear 2 steps ahead, skew provably < 2 steps.
template<bool LLC>
__device__ __forceinline__ void st1(u32* p, u32 v) {
    if constexpr (LLC)
        asm volatile("global_store_dword %0, %1, off sc0 sc1" :: "v"(p), "v"(v) : "memory");
    else
        asm volatile("global_store_dword %0, %1, off sc0" :: "v"(p), "v"(v) : "memory");
}
template<bool LLC>
__device__ __forceinline__ void ld4(u32x4& r, const u32* p) {
    if constexpr (LLC)
        asm volatile("global_load_dwordx4 %0, %1, off sc0 sc1" : "=v"(r) : "v"(p) : "memory");
    else
        asm volatile("global_load_dwordx4 %0, %1, off sc0" : "=v"(r) : "v"(p) : "memory");
}

struct Wf { bf16x8 v[16]; };

template<bool LLC>
__device__ __forceinline__ void lstm_loop(
    const Wf wf, const bft* __restrict__ gin, const u32* __restrict__ mbits,
    bft* __restrict__ ys, u32* __restrict__ hbase, u64* smem, int dir, int gslice)
{
    bft* hs  = (bft*)smem;                  // [32][512] bf16, 16B-block XOR swizzle
    u32* hsd = (u32*)smem;
    int t = threadIdx.x;
    int lane = t & 63, w = t >> 6;
    int lrow = lane & 15, quad = lane >> 4;
    int jw = w * 2 + (quad >> 1);           // this lane's j-pair within slice [0,8)
    int pw0 = gslice * 256 + lrow * 8 + jw; // publish word, cell0 (bat=lrow)
    int pw1 = pw0 + 128;                    // cell1 (bat=16+lrow)
    u32* ysU = (u32*)ys;
    float cs0 = 0.f, cs1 = 0.f, hp0 = 0.f, hp1 = 0.f;
    u32 mw0 = 0, mw1 = 0;

    for (int it = 0; it < 256; ++it) {
        int tt = dir ? (255 - it) : it;

        // gin: lane reads its 8 gates (2 cells x i,f,g,o) as one 16B load
        bf16x8 gv = *(const bf16x8*)(gin + (((size_t)tt * 32 + gslice) << 11) + t * 8);
        if ((it & 31) == 0) {
            mw0 = mbits[(tt >> 5) * 32 + lrow];
            mw1 = mbits[(tt >> 5) * 32 + 16 + lrow];
        }
        int mk0 = (mw0 >> (tt & 31)) & 1;
        int mk1 = (mw1 >> (tt & 31)) & 1;

        // rotation clear (own words of buf[(it+2)&3], fire-and-forget)
        if (!(lane & 16)) {
            u32* ca = hbase + (size_t)((it + 2) & 3) * 8192;
            st1<LLC>(ca + pw0, SENT);
            st1<LLC>(ca + pw1, SENT);
        }
        __syncthreads();                    // Spre: prev MFMA reads done before hs overwrite

        // poll + load buf[it&3] (8 x dwordx4/thread, per-chunk revalidate, backoff)
        const u32* hq = hbase + (size_t)(it & 3) * 8192 + t * 4;
        u32x4 r[8];
        u32 need = 0xffu;
        for (;;) {
#pragma unroll
            for (int i = 0; i < 8; ++i)
                if (need & (1u << i)) ld4<LLC>(r[i], hq + i * 1024);
            asm volatile("s_waitcnt vmcnt(0)" ::: "memory");
#pragma unroll
            for (int i = 0; i < 8; ++i)
                if ((need & (1u << i)) &&
                    r[i][0] != SENT && r[i][1] != SENT && r[i][2] != SENT && r[i][3] != SENT)
                    need &= ~(1u << i);
            if (!need) break;
            __builtin_amdgcn_s_sleep(1);
        }

        // stage into LDS (swizzled): chunk (i,t) = [gs=i*4+(t>>6)][bat=(t&63)>>1][jhalf=t&1]
#pragma unroll
        for (int i = 0; i < 8; ++i) {
            int gs  = i * 4 + (t >> 6);
            int bat = (t & 63) >> 1;
            int b16 = gs * 2 + (t & 1);
            *(u32x4*)(hsd + bat * 256 + ((b16 ^ (bat & 7)) << 2)) = r[i];
        }
        __syncthreads();                    // S2

        // gates^T = Whh_slice(64 rows) @ h^T : 2 col-blocks (batches 0-15 / 16-31)
        f32x4 aA = {}, aB = {}, aC = {}, aD = {};
#pragma unroll
        for (int kk = 0; kk < 16; ++kk) {
            int b16 = kk * 4 + quad;
            int bat1 = 16 + lrow;
            bf16x8 b0 = *(const bf16x8*)(hs + lrow * 512 + ((b16 ^ (lrow & 7)) << 3));
            bf16x8 b1 = *(const bf16x8*)(hs + bat1 * 512 + ((b16 ^ (bat1 & 7)) << 3));
            if (kk & 1) {
                aB = __builtin_amdgcn_mfma_f32_16x16x32_bf16(wf.v[kk], b0, aB, 0, 0, 0);
                aD = __builtin_amdgcn_mfma_f32_16x16x32_bf16(wf.v[kk], b1, aD, 0, 0, 0);
            } else {
                aA = __builtin_amdgcn_mfma_f32_16x16x32_bf16(wf.v[kk], b0, aA, 0, 0, 0);
                aC = __builtin_amdgcn_mfma_f32_16x16x32_bf16(wf.v[kk], b1, aC, 0, 0, 0);
            }
        }
        f32x4 a0 = aA + aB, a1 = aC + aD;   // lane: gates (i,f,g,o) of cells (j, lrow/16+lrow)

        // activation: 2 cells per lane, register-local
        float xi0 = a0[0] + (float)gv[0], xf0 = a0[1] + (float)gv[1];
        float xg0 = a0[2] + (float)gv[2], xo0 = a0[3] + (float)gv[3];
        float xi1 = a1[0] + (float)gv[4], xf1 = a1[1] + (float)gv[5];
        float xg1 = a1[2] + (float)gv[6], xo1 = a1[3] + (float)gv[7];
        float cn0 = sigmoidf_(xf0) * cs0 + sigmoidf_(xi0) * tanhf_(xg0);
        float cn1 = sigmoidf_(xf1) * cs1 + sigmoidf_(xi1) * tanhf_(xg1);
        float hn0 = sigmoidf_(xo0) * tanhf_(cn0);
        float hn1 = sigmoidf_(xo1) * tanhf_(cn1);
        if (mk0) { cs0 = cn0; hp0 = hn0; }
        if (mk1) { cs1 = cn1; hp1 = hn1; }
        union { bft h; unsigned short u; } h0c, h1c;
        h0c.h = (bft)hp0; h1c.h = (bft)hp1;
        u32 own0 = (u32)h0c.u | ((mk0 ? (u32)h0c.u : 0u) << 16);
        u32 own1 = (u32)h1c.u | ((mk1 ? (u32)h1c.u : 0u) << 16);
        u32 par0 = __shfl_xor(own0, 16, 64);    // partner quad^1 = j^1
        u32 par1 = __shfl_xor(own1, 16, 64);

        if (!(lane & 16)) {                     // even quads publish j-pairs
            u32 hw0 = (own0 & 0xffffu) | (par0 << 16);
            u32 hw1 = (own1 & 0xffffu) | (par1 << 16);
            u32 yw0 = (own0 >> 16) | (par0 & 0xffff0000u);
            u32 yw1 = (own1 >> 16) | (par1 & 0xffff0000u);
            u32* ha = hbase + (size_t)((it + 1) & 3) * 8192;
            st1<LLC>(ha + pw0, hw0);
            st1<LLC>(ha + pw1, hw1);
            // ys: plain cached stores, off critical path
            ysU[((size_t)tt * 32 + lrow) * 512 + dir * 256 + gslice * 8 + jw] = yw0;
            ysU[((size_t)tt * 32 + 16 + lrow) * 512 + dir * 256 + gslice * 8 + jw] = yw1;
        }
    }
}

__global__ __launch_bounds__(256) void bilstm_kernel(
    const bft* __restrict__ gin_f, const bft* __restrict__ gin_b,
    const bft* __restrict__ Whh_f, const bft* __restrict__ Whh_b,
    const u32* __restrict__ mbits, bft* __restrict__ ys,
    u32* __restrict__ hg, u32* __restrict__ probe)
{
    int blk = blockIdx.x;
    if ((blk & 7) > 1) return;          // only blk%8 in {0,1} participate
    int dir = blk & 7;                  // 0 = forward (XCD A), 1 = backward (XCD B)
    int gslice = blk >> 3;              // [0,32), 16 h-cols each
    const bft* Whh = dir ? Whh_b : Whh_f;
    const bft* gin = dir ? gin_b : gin_f;
    u32* hbase = hg + (size_t)dir * 4 * 8192;

    __shared__ u64 smem[4096];          // 32 KB h staging
    u32* hsd = (u32*)smem;

    int t = threadIdx.x;
    int lane = t & 63, w = t >> 6;
    int lrow = lane & 15, quad = lane >> 4;

    // ---- loop-invariant Whh fragments (wave w owns gatecol rows [w*16,(w+1)*16)) ----
    Wf wf;
    {
        int jl = w * 4 + (lrow >> 2), g = lrow & 3;   // row = j_local*4+g interleave
        const bft* wp = Whh + (size_t)(g * 512 + gslice * 16 + jl) * 512 + quad * 8;
#pragma unroll
        for (int kk = 0; kk < 16; ++kk)
            wf.v[kk] = *(const bf16x8*)(wp + kk * 32);
    }

    // ---- placement probe: is this dir's group L2-coherent? ----
    u32* pr = probe + dir * 32;
    u32* vd = probe + 64 + dir * 32;
    if (t == 0) {
        u32 m = MAGIC;
        asm volatile("global_store_dword %0, %1, off sc0" :: "v"(pr + gslice), "v"(m) : "memory");
    }
    int fast;
    {
        int ok = 0;
        if (w == 0) {
            const u32* pp = pr + (lane & 31);
            for (int rd = 0; rd < 96; ++rd) {
                u32 v;
                asm volatile("global_load_dword %0, %1, off sc0" : "=v"(v) : "v"(pp) : "memory");
                asm volatile("s_waitcnt vmcnt(0)" ::: "memory");
                if (__all(v == MAGIC)) { ok = 1; break; }
                __builtin_amdgcn_s_sleep(4);
            }
        }
        if (t == 0) hsd[0] = (u32)ok;
        __syncthreads();
        ok = (int)hsd[0];
        __syncthreads();
        // consensus via LLC (always coherent): fast only if ALL 32 WGs probed OK
        if (t == 0) {
            u32 v = ok ? 1u : 2u;
            asm volatile("global_store_dword %0, %1, off sc0 sc1" :: "v"(vd + gslice), "v"(v) : "memory");
        }
        int f2 = 0;
        if (w == 0) {
            const u32* pp = vd + (lane & 31);
            for (;;) {
                u32 v;
                asm volatile("global_load_dword %0, %1, off sc0 sc1" : "=v"(v) : "v"(pp) : "memory");
                asm volatile("s_waitcnt vmcnt(0)" ::: "memory");
                if (__all(v != 0u)) { f2 = __all(v == 1u) ? 1 : 0; break; }
                __builtin_amdgcn_s_sleep(4);
            }
        }
        if (t == 0) hsd[0] = (u32)f2;
        __syncthreads();
        fast = (int)hsd[0];
        __syncthreads();
    }

    if (fast) lstm_loop<false>(wf, gin, mbits, ys, hbase, smem, dir, gslice);
    else      lstm_loop<true >(wf, gin, mbits, ys, hbase, smem, dir, gslice);
}

// ---------- host launcher ----------
extern "C" void kernel_launch(void* const* d_in, const int* in_sizes, int n_in,
                              void* d_out, int out_size, void* d_ws, size_t ws_size,
                              hipStream_t stream)
{
    const float* X     = (const float*)d_in[0];   // [32,256,1024]
    const int*   amask = (const int*)d_in[1];     // [32,256]
    const int*   langs = (const int*)d_in[2];     // [32]
    const float* W1    = (const float*)d_in[3];   // [5,1024,1024] (K-major)
    const float* b1    = (const float*)d_in[4];   // [5,1024]
    const float* ln_g  = (const float*)d_in[5];
    const float* ln_b  = (const float*)d_in[6];
    const float* W2    = (const float*)d_in[7];
    const float* b2    = (const float*)d_in[8];
    const float* Wih_f = (const float*)d_in[9];   // [2048,1024] = [N][K]
    const float* Whh_f = (const float*)d_in[10];  // [2048,512]
    const float* b_f   = (const float*)d_in[11];  // [2048]
    const float* Wih_b = (const float*)d_in[12];
    const float* Whh_b = (const float*)d_in[13];
    const float* b_b   = (const float*)d_in[14];
    const float* Wp    = (const float*)d_in[15];  // [256,1024] = [N][K]
    const float* bp    = (const float*)d_in[16];
    float* out = (float*)d_out;

    char* ws = (char*)d_ws;
    size_t off = 0;
    auto alloc = [&](size_t bytes) -> void* {
        void* p = ws + off;
        off += (bytes + 255) & ~(size_t)255;
        return p;
    };
    bft* Xbf   = (bft*)alloc(8192ull * 1024 * 2);
    bft* W1t   = (bft*)alloc(5ull * 1024 * 1024 * 2);
    bft* W2t   = (bft*)alloc(5ull * 1024 * 1024 * 2);
    bft* Wihf  = (bft*)alloc(2048ull * 1024 * 2);
    bft* Wihb  = (bft*)alloc(2048ull * 1024 * 2);
    bft* Whhf  = (bft*)alloc(2048ull * 512 * 2);
    bft* Whhb  = (bft*)alloc(2048ull * 512 * 2);
    bft* Wpb   = (bft*)alloc(256ull * 1024 * 2);
    float* h1  = (float*)alloc(8192ull * 1024 * 4);
    bft* a2    = (bft*)alloc(8192ull * 1024 * 2);
    bft* adapt = (bft*)alloc(8192ull * 1024 * 2);
    bft* ginf  = (bft*)alloc(256ull * 32 * 2048 * 2);
    bft* ginb  = (bft*)alloc(256ull * 32 * 2048 * 2);
    bft* ysb   = (bft*)alloc(256ull * 32 * 1024 * 2);
    float* pbf = (float*)alloc(2048ull * 4);
    float* pbb = (float*)alloc(2048ull * 4);
    u32* hg    = (u32*)alloc(2ull * 4 * 8192 * 4);   // [dir][buf4][gs][bat][jw], 256 KB
    u32* mbits = (u32*)alloc(256ull * 4);
    u32* probe = (u32*)alloc(128ull * 4);            // probe[2][32] + verdict[2][32]
    (void)ws_size; (void)in_sizes; (void)n_in; (void)out_size;

    auto cvt = [&](const float* src, bft* dst, int n) {
        int n4 = n >> 2;
        hipLaunchKernelGGL(cvt_f32_bf16, dim3((n4 + 255) / 256), dim3(256), 0, stream, src, dst, n4);
    };
    cvt(X, Xbf, 8192 * 1024);
    hipLaunchKernelGGL(cvt_permute_wih, dim3(2048), dim3(256), 0, stream, Wih_f, Wihf);
    hipLaunchKernelGGL(cvt_permute_wih, dim3(2048), dim3(256), 0, stream, Wih_b, Wihb);
    cvt(Whh_f, Whhf, 2048 * 512);
    cvt(Whh_b, Whhb, 2048 * 512);
    cvt(Wp, Wpb, 256 * 1024);
    hipLaunchKernelGGL(permute_bias, dim3(8), dim3(256), 0, stream, b_f, pbf);
    hipLaunchKernelGGL(permute_bias, dim3(8), dim3(256), 0, stream, b_b, pbb);
    hipLaunchKernelGGL(init_hg, dim3(256), dim3(256), 0, stream, hg);
    hipLaunchKernelGGL(zero_u32, dim3(1), dim3(256), 0, stream, probe, 128);
    hipLaunchKernelGGL(pack_mask, dim3(1), dim3(256), 0, stream, amask, mbits);
    hipLaunchKernelGGL(transpose_cvt_w, dim3(32, 32, 10), dim3(256), 0, stream, W1, W2, W1t, W2t);

    // Adapter GEMM1: h1 = X @ W1[lang] + b1[lang]   (f32 out for LN)
    hipLaunchKernelGGL(gemm_bt, dim3(8, 64), dim3(256), 0, stream,
        Xbf, W1t, b1, langs, 1024 * 1024, 1024, h1, (bft*)nullptr, 0, 0, 1024);
    // LN + ReLU -> a2 (bf16)
    hipLaunchKernelGGL(ln_relu_kernel, dim3(8192), dim3(256), 0, stream, h1, a2, ln_g, ln_b, langs);
    // Adapter GEMM2: adapt = a2 @ W2[lang] + b2[lang]   (bf16 out)
    hipLaunchKernelGGL(gemm_bt, dim3(8, 64), dim3(256), 0, stream,
        a2, W2t, b2, langs, 1024 * 1024, 1024, (float*)nullptr, adapt, 0, 0, 1024);
    // Input gates (gate-interleaved, bilstm-coalesced 32-gslice layout): remapLog = -1
    hipLaunchKernelGGL(gemm_bt, dim3(16, 64), dim3(256), 0, stream,
        adapt, Wihf, pbf, (const int*)nullptr, 0, 0, (float*)nullptr, ginf, -1, 0, 0);
    hipLaunchKernelGGL(gemm_bt, dim3(16, 64), dim3(256), 0, stream,
        adapt, Wihb, pbb, (const int*)nullptr, 0, 0, (float*)nullptr, ginb, -1, 0, 0);
    // Recurrence: 256 blocks so blk%8 in {0,1} selects 32 WGs per XCD per direction
    {
        void* args[] = { (void*)&ginf, (void*)&ginb, (void*)&Whhf, (void*)&Whhb,
                         (void*)&mbits, (void*)&ysb, (void*)&hg, (void*)&probe };
        hipLaunchCooperativeKernel((const void*)bilstm_kernel, dim3(256), dim3(256), args, 0, stream);
    }
    // Projection: out = ys @ Wp^T + bp, remap row (s*32+b) -> (b*256+s), ldc 256
    hipLaunchKernelGGL(gemm_bt, dim3(2, 64), dim3(256), 0, stream,
        ysb, Wpb, bp, (const int*)nullptr, 0, 0, out, (bft*)nullptr, 5, 256, 256);
}

// Round 7
// 1510.209 us; speedup vs baseline: 1.8087x; 1.1212x over previous
//
#include <hip/hip_runtime.h>

// ---------- types ----------
typedef __bf16 bft;
typedef bft bf16x8 __attribute__((ext_vector_type(8)));
typedef bft bf16x4 __attribute__((ext_vector_type(4)));
typedef bft bf16x2 __attribute__((ext_vector_type(2)));
typedef float f32x4 __attribute__((ext_vector_type(4)));
typedef unsigned long long u64;
typedef unsigned int u32;
typedef u32 u32x4 __attribute__((ext_vector_type(4)));

#define LN_EPS 1e-5f
#define SENT 0x7FC17FC1u   // bf16-pair NaN pattern: impossible for |h|<=1 outputs

// B=32, S=256, H=1024, HL=512, E=256, L=5. All big GEMMs have K=1024.

__device__ __forceinline__ float sigmoidf_(float x) {
    return 1.f / (1.f + __expf(-x));
}
__device__ __forceinline__ float tanhf_(float x) {
    float e = __expf(-2.f * fabsf(x));
    float t = (1.f - e) / (1.f + e);
    return copysignf(t, x);
}

// ---------- f32 -> bf16 convert (vector-4) ----------
__global__ void cvt_f32_bf16(const float* __restrict__ in, bft* __restrict__ out, int n4) {
    int i = blockIdx.x * blockDim.x + threadIdx.x;
    if (i < n4) {
        float4 v = ((const float4*)in)[i];
        bf16x4 o = { (bft)v.x, (bft)v.y, (bft)v.z, (bft)v.w };
        ((bf16x4*)out)[i] = o;
    }
}

// ---------- hg init: buf0 = 0 (valid h0), buf1..3 = sentinel ----------
// hg layout: [dir(2)][buf(4)][gs(64)][bat(32)][jp(4)] u32
__global__ void init_hg(u32* __restrict__ hg) {
    int i = blockIdx.x * blockDim.x + threadIdx.x;   // 65536
    int buf = (i >> 13) & 3;
    hg[i] = (buf == 0) ? 0u : SENT;
}

// ---------- mask bit-pack: mask[32][256] int -> mbits[w(8)][batch(32)] u32 ----------
__global__ void pack_mask(const int* __restrict__ mask, u32* __restrict__ mbits) {
    int t = blockIdx.x * blockDim.x + threadIdx.x;
    if (t < 256) {
        int w = t >> 5, b = t & 31;
        u32 v = 0;
        for (int i = 0; i < 32; ++i)
            v |= (mask[b * 256 + w * 32 + i] ? 1u : 0u) << i;
        mbits[w * 32 + b] = v;
    }
}

// ---------- Wih convert with gate-interleave row permutation ----------
// dest row r' = j*4+g  <-  src row g*512+j   (so gin cols become [j][gate])
__global__ __launch_bounds__(256) void cvt_permute_wih(
    const float* __restrict__ in, bft* __restrict__ out)
{
    int r = blockIdx.x;                       // 0..2047 dest row
    int src = (r & 3) * 512 + (r >> 2);
    int t = threadIdx.x;
    float4 v = ((const float4*)(in + (size_t)src * 1024))[t];
    bf16x4 o = { (bft)v.x, (bft)v.y, (bft)v.z, (bft)v.w };
    ((bf16x4*)(out + (size_t)r * 1024))[t] = o;
}

__global__ void permute_bias(const float* __restrict__ in, float* __restrict__ out) {
    int t = blockIdx.x * blockDim.x + threadIdx.x;
    if (t < 2048) out[t] = in[(t & 3) * 512 + (t >> 2)];
}

// ---------- transpose+convert W1/W2 ([L][K=h][N=d] f32 -> [L][N][K] bf16) ----------
__global__ __launch_bounds__(256) void transpose_cvt_w(
    const float* __restrict__ W1, const float* __restrict__ W2,
    bft* __restrict__ W1t, bft* __restrict__ W2t)
{
    __shared__ float tile[32][33];
    int z = blockIdx.z;
    int l = z >> 1;
    const float* src = ((z & 1) ? W2 : W1) + ((size_t)l << 20);
    bft* dst = ((z & 1) ? W2t : W1t) + ((size_t)l << 20);
    int tx = threadIdx.x & 31, ty = threadIdx.x >> 5;
    int bx = blockIdx.x * 32, by = blockIdx.y * 32;
    for (int r = ty; r < 32; r += 8)
        tile[r][tx] = src[(size_t)(by + r) * 1024 + bx + tx];
    __syncthreads();
    for (int r = ty; r < 32; r += 8)
        dst[(size_t)(bx + r) * 1024 + by + tx] = (bft)tile[tx][r];
}

// ---------- bf16 MFMA GEMM, 128x128 tile, BK=32, 4 waves, global_load_lds staging ----------
// remapLog >= 0: row remap. remapLog < 0: gin mode (bilstm-coalesced, 64 gslices).
__global__ __launch_bounds__(256) void gemm_bt(
    const bft* __restrict__ A, const bft* __restrict__ Bt,
    const float* __restrict__ bias, const int* __restrict__ langs,
    int langStrideB, int langStrideBias,
    float* __restrict__ outF, bft* __restrict__ outB,
    int remapLog, int remapMul, int ldc)
{
    const int K = 1024;
    int tn = blockIdx.x, tm = blockIdx.y;
    int row0 = tm * 128, col0 = tn * 128;
    int lang = langs ? langs[row0 >> 8] : 0;
    const bft* Ap = A + (size_t)row0 * K;
    const bft* Bp = Bt + (size_t)lang * langStrideB + (size_t)col0 * K;
    const float* biasp = bias + (size_t)lang * langStrideBias + col0;

    __shared__ bft As[128 * 32];
    __shared__ bft Bs[128 * 32];

    int t = threadIdx.x;
    int lane = t & 63, wave = t >> 6;
    int wm = wave & 1, wn = wave >> 1;
    int lrow = lane & 15, quad = lane >> 4;

    f32x4 acc[4][4] = {};

    for (int k0 = 0; k0 < K; k0 += 32) {
        __syncthreads();
#pragma unroll
        for (int c0 = 0; c0 < 512; c0 += 256) {
            int c = c0 + t;
            int r = c >> 2, co = (c & 3) << 3;
            __builtin_amdgcn_global_load_lds(
                (const __attribute__((address_space(1))) u32*)(Ap + (size_t)r * K + k0 + co),
                (__attribute__((address_space(3))) u32*)(As + c * 8), 16, 0, 0);
            __builtin_amdgcn_global_load_lds(
                (const __attribute__((address_space(1))) u32*)(Bp + (size_t)r * K + k0 + co),
                (__attribute__((address_space(3))) u32*)(Bs + c * 8), 16, 0, 0);
        }
        __syncthreads();
        bf16x8 af[4], bfr[4];
#pragma unroll
        for (int i = 0; i < 4; ++i)
            af[i] = *(const bf16x8*)(As + (wm * 64 + i * 16 + lrow) * 32 + quad * 8);
#pragma unroll
        for (int j = 0; j < 4; ++j)
            bfr[j] = *(const bf16x8*)(Bs + (wn * 64 + j * 16 + lrow) * 32 + quad * 8);
#pragma unroll
        for (int i = 0; i < 4; ++i)
#pragma unroll
            for (int j = 0; j < 4; ++j)
                acc[i][j] = __builtin_amdgcn_mfma_f32_16x16x32_bf16(af[i], bfr[j], acc[i][j], 0, 0, 0);
    }

#pragma unroll
    for (int i = 0; i < 4; ++i) {
#pragma unroll
        for (int j = 0; j < 4; ++j) {
#pragma unroll
            for (int r = 0; r < 4; ++r) {
                int m = wm * 64 + i * 16 + quad * 4 + r;
                int n = wn * 64 + j * 16 + lrow;
                int grow = row0 + m;
                float v = acc[i][j][r] + biasp[n];
                size_t idx;
                if (remapLog < 0) {
                    // gin layout: [s][gslice(64)][tc(256)*4 + gate]
                    int b = grow >> 8, s = grow & 255;
                    int col = col0 + n;
                    int jj = col >> 2, gg = col & 3;
                    int jp = jj & 7, gs = jj >> 3;
                    int tc = (((b >> 4) * 2 + (jp >> 2)) << 6) + ((jp & 3) << 4) + (b & 15);
                    idx = (((size_t)s * 64 + gs) << 10) + (tc << 2) + gg;
                } else {
                    int orow = remapLog ? ((grow & ((1 << remapLog) - 1)) * remapMul + (grow >> remapLog))
                                        : grow;
                    idx = (size_t)orow * ldc + col0 + n;
                }
                if (outF) outF[idx] = v;
                else outB[idx] = (bft)v;
            }
        }
    }
}

// ---------- LayerNorm + ReLU per row, f32 in -> bf16 out ----------
__global__ __launch_bounds__(256) void ln_relu_kernel(
    const float* __restrict__ h1, bft* __restrict__ a2,
    const float* __restrict__ ln_g, const float* __restrict__ ln_b,
    const int* __restrict__ langs)
{
    int row = blockIdx.x;
    int lang = langs[row >> 8];
    const float* x = h1 + (size_t)row * 1024;
    int t = threadIdx.x;
    float4 v = ((const float4*)x)[t];
    float s = v.x + v.y + v.z + v.w;
    float ss = v.x * v.x + v.y * v.y + v.z * v.z + v.w * v.w;
#pragma unroll
    for (int off = 32; off > 0; off >>= 1) {
        s += __shfl_down(s, off, 64);
        ss += __shfl_down(ss, off, 64);
    }
    __shared__ float red[8];
    int wave = t >> 6, lane = t & 63;
    if (lane == 0) { red[wave] = s; red[4 + wave] = ss; }
    __syncthreads();
    float S = red[0] + red[1] + red[2] + red[3];
    float SS = red[4] + red[5] + red[6] + red[7];
    float mean = S * (1.f / 1024.f);
    float var = SS * (1.f / 1024.f) - mean * mean;
    float inv = rsqrtf(var + LN_EPS);
    float4 g = ((const float4*)(ln_g + (size_t)lang * 1024))[t];
    float4 b = ((const float4*)(ln_b + (size_t)lang * 1024))[t];
    float y0 = fmaxf(0.f, (v.x - mean) * inv * g.x + b.x);
    float y1 = fmaxf(0.f, (v.y - mean) * inv * g.y + b.y);
    float y2 = fmaxf(0.f, (v.z - mean) * inv * g.z + b.z);
    float y3 = fmaxf(0.f, (v.w - mean) * inv * g.w + b.w);
    bf16x4 o = { (bft)y0, (bft)y1, (bft)y2, (bft)y3 };
    ((bf16x4*)(a2 + (size_t)row * 1024))[t] = o;
}

// ---------- BiLSTM recurrence: fwd/bwd interleaved in ONE WG (latency hiding) ----------
// 64 WGs, WG g owns h-cols [g*8,(g+1)*8) of BOTH directions. Per superstep:
//   poll_f -> MFMA_f -> publish_f -> poll_b -> MFMA_b -> publish_b
// Each direction's publish->observe round trip (the measured ~5-6k cyc floor) is hidden
// behind the OTHER direction's entire phase -> period per superstep = RT + one phase,
// i.e. per-LSTM-step cost halves vs R4. Sentinel protocol per dir unchanged (R4-proven):
// 4 rotating buffers, data self-validating (!= SENT), fire-and-forget publishes,
// rotation clear 2 steps ahead (drained by the poll's own vmcnt(0) before re-publish).
// Barriers: 1 per LSTM step (each phase's post-stage barrier covers the other buffer's
// WAR hazard from the previous superstep).
__device__ __forceinline__ void poll_stage(const u32* __restrict__ hq0,
                                           u32* __restrict__ hsd, int t)
{
    const u32* hq = hq0 + t * 4;
    u32x4 r[8];
    u32 need = 0xffu;
    for (;;) {
#pragma unroll
        for (int i = 0; i < 8; ++i)
            if (need & (1u << i))
                asm volatile("global_load_dwordx4 %0, %1, off sc0 sc1"
                             : "=v"(r[i]) : "v"(hq + i * 1024) : "memory");
        asm volatile("s_waitcnt vmcnt(0)" ::: "memory");
#pragma unroll
        for (int i = 0; i < 8; ++i)
            if ((need & (1u << i)) &&
                r[i][0] != SENT && r[i][1] != SENT && r[i][2] != SENT && r[i][3] != SENT)
                need &= ~(1u << i);
        if (!need) break;
        __builtin_amdgcn_s_sleep(1);
    }
#pragma unroll
    for (int i = 0; i < 8; ++i) {
        int bat = t & 31, gs = i * 8 + (t >> 5);       // chunk: [gs][bat][jp0..3]
        *(u32x4*)(hsd + bat * 256 + ((gs ^ (bat & 7)) << 2)) = r[i];
    }
}

__device__ __forceinline__ void step_phase(
    const bf16x8* __restrict__ wf, const bft* __restrict__ hs,
    int batch, int quad, bf16x4 gv, int mk,
    float& cs, float& hp, u32& hpair, u32& ypair)
{
    f32x4 acc0 = {}, acc1 = {};
#pragma unroll
    for (int kk = 0; kk < 16; ++kk) {
        int b16 = kk * 4 + quad;
        bf16x8 b = *(const bf16x8*)(hs + batch * 512 + ((b16 ^ (batch & 7)) << 3));
        if (kk & 1) acc1 = __builtin_amdgcn_mfma_f32_16x16x32_bf16(wf[kk], b, acc1, 0, 0, 0);
        else        acc0 = __builtin_amdgcn_mfma_f32_16x16x32_bf16(wf[kk], b, acc0, 0, 0, 0);
    }
    f32x4 acc = acc0 + acc1;
    float xi = acc[0] + (float)gv[0];
    float xf = acc[1] + (float)gv[1];
    float xg = acc[2] + (float)gv[2];
    float xo = acc[3] + (float)gv[3];
    float cn = sigmoidf_(xf) * cs + sigmoidf_(xi) * tanhf_(xg);
    float hn = sigmoidf_(xo) * tanhf_(cn);
    if (mk) { cs = cn; hp = hn; }
    union { bft h; unsigned short u; } hc; hc.h = (bft)hp;
    u32 own = (u32)hc.u | ((mk ? (u32)hc.u : 0u) << 16);   // low: h16, high: y16
    u32 par = __shfl_xor(own, 16, 64);                     // partner = quad^1 (j +/- 1)
    hpair = (own & 0xffffu) | (par << 16);
    ypair = (own >> 16) | (par & 0xffff0000u);
}

__global__ __launch_bounds__(256, 1) void bilstm_kernel(
    const bft* __restrict__ gin_f, const bft* __restrict__ gin_b,
    const bft* __restrict__ Whh_f, const bft* __restrict__ Whh_b,
    const u32* __restrict__ mbits, bft* __restrict__ ys,
    u32* __restrict__ hg)
{
    __shared__ u64 smem[8192];                 // 64 KB: two h staging buffers
    bft* hsf  = (bft*)smem;                    // fwd [32][512] bf16, swizzled
    u32* hsfd = (u32*)smem;
    bft* hsb  = (bft*)(smem + 4096);           // bwd
    u32* hsbd = (u32*)(smem + 4096);

    int gslice = blockIdx.x;            // [0,64)
    int jbase = gslice << 3;
    u32* hbf = hg;                      // fwd exchange base
    u32* hbb = hg + 4 * 8192;           // bwd exchange base

    int t = threadIdx.x;
    int lane = t & 63, wave = t >> 6;
    int wm = wave & 1, wn = wave >> 1;
    int lrow = lane & 15, quad = lane >> 4;

    // ---- loop-invariant Whh fragments for BOTH dirs (rows interleaved j*4+g) ----
    bf16x8 wff[16], wfb[16];
    {
        int row32 = wm * 16 + lrow;
        int jl = row32 >> 2, g = row32 & 3;
        const bft* wpf = Whh_f + (size_t)(g * 512 + jbase + jl) * 512 + quad * 8;
        const bft* wpb = Whh_b + (size_t)(g * 512 + jbase + jl) * 512 + quad * 8;
#pragma unroll
        for (int kk = 0; kk < 16; ++kk) {
            wff[kk] = *(const bf16x8*)(wpf + kk * 32);
            wfb[kk] = *(const bf16x8*)(wpb + kk * 32);
        }
    }

    int batch = wn * 16 + lrow;
    int pword = gslice * 128 + batch * 4 + wm * 2 + (quad >> 1);   // publish word (even quads)
    u32* ysU = (u32*)ys;
    float csf = 0.f, hpf = 0.f, csb = 0.f, hpb = 0.f;
    u32 mwf = 0, mwb = 0;

    for (int it = 0; it < 256; ++it) {
        int ttf = it, ttb = 255 - it;

        // gin prefetch for both dirs (8B/lane each, contiguous 2KB per WG)
        bf16x4 gvf = *(const bf16x4*)(gin_f + ((((size_t)ttf * 64 + gslice) << 10) + (t << 2)));
        bf16x4 gvb = *(const bf16x4*)(gin_b + ((((size_t)ttb * 64 + gslice) << 10) + (t << 2)));
        if ((it & 31) == 0) {
            mwf = mbits[(ttf >> 5) * 32 + batch];
            mwb = mbits[(ttb >> 5) * 32 + batch];
        }
        int mkf = (mwf >> (ttf & 31)) & 1;
        int mkb = (mwb >> (ttb & 31)) & 1;

        // rotation clear (both dirs, own words of buf[(it+2)&3], fire & forget;
        // drained by the fwd poll's vmcnt(0) below)
        if (!(lane & 16)) {
            u32 sv = SENT;
            u32* caf = hbf + (size_t)((it + 2) & 3) * 8192 + pword;
            u32* cab = hbb + (size_t)((it + 2) & 3) * 8192 + pword;
            asm volatile("global_store_dword %0, %1, off sc0 sc1" :: "v"(caf), "v"(sv) : "memory");
            asm volatile("global_store_dword %0, %1, off sc0 sc1" :: "v"(cab), "v"(sv) : "memory");
        }

        // ================= FWD phase =================
        poll_stage(hbf + (size_t)(it & 3) * 8192, hsfd, t);
        __syncthreads();    // Sf: hsf staged; also covers WAR on hsb (prev MFMA_b readers)
        u32 hwf, ywf;
        step_phase(wff, hsf, batch, quad, gvf, mkf, csf, hpf, hwf, ywf);
        if (!(lane & 16)) {
            u32* ha = hbf + (size_t)((it + 1) & 3) * 8192 + pword;
            asm volatile("global_store_dword %0, %1, off sc0 sc1" :: "v"(ha), "v"(hwf) : "memory");
            ysU[((size_t)ttf * 32 + batch) * 512 + (gslice << 2) + wm * 2 + (quad >> 1)] = ywf;
        }

        // ================= BWD phase =================
        poll_stage(hbb + (size_t)(it & 3) * 8192, hsbd, t);
        __syncthreads();    // Sb: hsb staged; also covers WAR on hsf (this step's MFMA_f readers)
        u32 hwb, ywb;
        step_phase(wfb, hsb, batch, quad, gvb, mkb, csb, hpb, hwb, ywb);
        if (!(lane & 16)) {
            u32* ha = hbb + (size_t)((it + 1) & 3) * 8192 + pword;
            asm volatile("global_store_dword %0, %1, off sc0 sc1" :: "v"(ha), "v"(hwb) : "memory");
            ysU[((size_t)ttb * 32 + batch) * 512 + 256 + (gslice << 2) + wm * 2 + (quad >> 1)] = ywb;
        }
    }
}

// ---------- host launcher ----------
extern "C" void kernel_launch(void* const* d_in, const int* in_sizes, int n_in,
                              void* d_out, int out_size, void* d_ws, size_t ws_size,
                              hipStream_t stream)
{
    const float* X     = (const float*)d_in[0];   // [32,256,1024]
    const int*   amask = (const int*)d_in[1];     // [32,256]
    const int*   langs = (const int*)d_in[2];     // [32]
    const float* W1    = (const float*)d_in[3];   // [5,1024,1024] (K-major)
    const float* b1    = (const float*)d_in[4];   // [5,1024]
    const float* ln_g  = (const float*)d_in[5];
    const float* ln_b  = (const float*)d_in[6];
    const float* W2    = (const float*)d_in[7];
    const float* b2    = (const float*)d_in[8];
    const float* Wih_f = (const float*)d_in[9];   // [2048,1024] = [N][K]
    const float* Whh_f = (const float*)d_in[10];  // [2048,512]
    const float* b_f   = (const float*)d_in[11];  // [2048]
    const float* Wih_b = (const float*)d_in[12];
    const float* Whh_b = (const float*)d_in[13];
    const float* b_b   = (const float*)d_in[14];
    const float* Wp    = (const float*)d_in[15];  // [256,1024] = [N][K]
    const float* bp    = (const float*)d_in[16];
    float* out = (float*)d_out;

    char* ws = (char*)d_ws;
    size_t off = 0;
    auto alloc = [&](size_t bytes) -> void* {
        void* p = ws + off;
        off += (bytes + 255) & ~(size_t)255;
        return p;
    };
    bft* Xbf   = (bft*)alloc(8192ull * 1024 * 2);
    bft* W1t   = (bft*)alloc(5ull * 1024 * 1024 * 2);
    bft* W2t   = (bft*)alloc(5ull * 1024 * 1024 * 2);
    bft* Wihf  = (bft*)alloc(2048ull * 1024 * 2);
    bft* Wihb  = (bft*)alloc(2048ull * 1024 * 2);
    bft* Whhf  = (bft*)alloc(2048ull * 512 * 2);
    bft* Whhb  = (bft*)alloc(2048ull * 512 * 2);
    bft* Wpb   = (bft*)alloc(256ull * 1024 * 2);
    float* h1  = (float*)alloc(8192ull * 1024 * 4);
    bft* a2    = (bft*)alloc(8192ull * 1024 * 2);
    bft* adapt = (bft*)alloc(8192ull * 1024 * 2);
    bft* ginf  = (bft*)alloc(256ull * 32 * 2048 * 2);
    bft* ginb  = (bft*)alloc(256ull * 32 * 2048 * 2);
    bft* ysb   = (bft*)alloc(256ull * 32 * 1024 * 2);
    float* pbf = (float*)alloc(2048ull * 4);             // permuted b_f
    float* pbb = (float*)alloc(2048ull * 4);             // permuted b_b
    u32* hg    = (u32*)alloc(2ull * 4 * 8192 * 4);       // [dir][buf4][gs][bat][jp], 256 KB
    u32* mbits = (u32*)alloc(256ull * 4);                // packed mask bits
    (void)ws_size; (void)in_sizes; (void)n_in; (void)out_size;

    auto cvt = [&](const float* src, bft* dst, int n) {
        int n4 = n >> 2;
        hipLaunchKernelGGL(cvt_f32_bf16, dim3((n4 + 255) / 256), dim3(256), 0, stream, src, dst, n4);
    };
    cvt(X, Xbf, 8192 * 1024);
    hipLaunchKernelGGL(cvt_permute_wih, dim3(2048), dim3(256), 0, stream, Wih_f, Wihf);
    hipLaunchKernelGGL(cvt_permute_wih, dim3(2048), dim3(256), 0, stream, Wih_b, Wihb);
    cvt(Whh_f, Whhf, 2048 * 512);
    cvt(Whh_b, Whhb, 2048 * 512);
    cvt(Wp, Wpb, 256 * 1024);
    hipLaunchKernelGGL(permute_bias, dim3(8), dim3(256), 0, stream, b_f, pbf);
    hipLaunchKernelGGL(permute_bias, dim3(8), dim3(256), 0, stream, b_b, pbb);
    hipLaunchKernelGGL(init_hg, dim3(256), dim3(256), 0, stream, hg);
    hipLaunchKernelGGL(pack_mask, dim3(1), dim3(256), 0, stream, amask, mbits);
    hipLaunchKernelGGL(transpose_cvt_w, dim3(32, 32, 10), dim3(256), 0, stream, W1, W2, W1t, W2t);

    // Adapter GEMM1: h1 = X @ W1[lang] + b1[lang]   (f32 out for LN)
    hipLaunchKernelGGL(gemm_bt, dim3(8, 64), dim3(256), 0, stream,
        Xbf, W1t, b1, langs, 1024 * 1024, 1024, h1, (bft*)nullptr, 0, 0, 1024);
    // LN + ReLU -> a2 (bf16)
    hipLaunchKernelGGL(ln_relu_kernel, dim3(8192), dim3(256), 0, stream, h1, a2, ln_g, ln_b, langs);
    // Adapter GEMM2: adapt = a2 @ W2[lang] + b2[lang]   (bf16 out)
    hipLaunchKernelGGL(gemm_bt, dim3(8, 64), dim3(256), 0, stream,
        a2, W2t, b2, langs, 1024 * 1024, 1024, (float*)nullptr, adapt, 0, 0, 1024);
    // Input gates (gate-interleaved, bilstm-coalesced 64-gslice layout): remapLog = -1
    hipLaunchKernelGGL(gemm_bt, dim3(16, 64), dim3(256), 0, stream,
        adapt, Wihf, pbf, (const int*)nullptr, 0, 0, (float*)nullptr, ginf, -1, 0, 0);
    hipLaunchKernelGGL(gemm_bt, dim3(16, 64), dim3(256), 0, stream,
        adapt, Wihb, pbb, (const int*)nullptr, 0, 0, (float*)nullptr, ginb, -1, 0, 0);
    // Recurrence: 64 WGs, each owns both directions of its slice (cooperative launch)
    {
        void* args[] = { (void*)&ginf, (void*)&ginb, (void*)&Whhf, (void*)&Whhb,
                         (void*)&mbits, (void*)&ysb, (void*)&hg };
        hipLaunchCooperativeKernel((const void*)bilstm_kernel, dim3(64), dim3(256), args, 0, stream);
    }
    // Projection: out = ys @ Wp^T + bp, remap row (s*32+b) -> (b*256+s), ldc 256
    hipLaunchKernelGGL(gemm_bt, dim3(2, 64), dim3(256), 0, stream,
        ysb, Wpb, bp, (const int*)nullptr, 0, 0, out, (bft*)nullptr, 5, 256, 256);
}

// Round 9
// 1183.544 us; speedup vs baseline: 2.3080x; 1.2760x over previous
//
#include <hip/hip_runtime.h>

// ---------- types ----------
typedef __bf16 bft;
typedef bft bf16x8 __attribute__((ext_vector_type(8)));
typedef bft bf16x4 __attribute__((ext_vector_type(4)));
typedef bft bf16x2 __attribute__((ext_vector_type(2)));
typedef float f32x4 __attribute__((ext_vector_type(4)));
typedef unsigned long long u64;
typedef unsigned int u32;
typedef u32 u32x4 __attribute__((ext_vector_type(4)));

#define LN_EPS 1e-5f

// B=32, S=256, H=1024, HL=512, E=256, L=5. All big GEMMs have K=1024.

__device__ __forceinline__ float sigmoidf_(float x) {
    return 1.f / (1.f + __expf(-x));
}
__device__ __forceinline__ float tanhf_(float x) {
    float e = __expf(-2.f * fabsf(x));
    float t = (1.f - e) / (1.f + e);
    return copysignf(t, x);
}

// ---------- f32 -> bf16 convert (vector-4) ----------
__global__ void cvt_f32_bf16(const float* __restrict__ in, bft* __restrict__ out, int n4) {
    int i = blockIdx.x * blockDim.x + threadIdx.x;
    if (i < n4) {
        float4 v = ((const float4*)in)[i];
        bf16x4 o = { (bft)v.x, (bft)v.y, (bft)v.z, (bft)v.w };
        ((bf16x4*)out)[i] = o;
    }
}

__global__ void zero_u32(u32* __restrict__ p, int n) {
    int i = blockIdx.x * blockDim.x + threadIdx.x;
    if (i < n) p[i] = 0u;
}

// ---------- transpose+convert W1/W2 ([L][K=h][N=d] f32 -> [L][N][K] bf16) ----------
__global__ __launch_bounds__(256) void transpose_cvt_w(
    const float* __restrict__ W1, const float* __restrict__ W2,
    bft* __restrict__ W1t, bft* __restrict__ W2t)
{
    __shared__ float tile[32][33];
    int z = blockIdx.z;
    int l = z >> 1;
    const float* src = ((z & 1) ? W2 : W1) + ((size_t)l << 20);
    bft* dst = ((z & 1) ? W2t : W1t) + ((size_t)l << 20);
    int tx = threadIdx.x & 31, ty = threadIdx.x >> 5;
    int bx = blockIdx.x * 32, by = blockIdx.y * 32;
    for (int r = ty; r < 32; r += 8)
        tile[r][tx] = src[(size_t)(by + r) * 1024 + bx + tx];
    __syncthreads();
    for (int r = ty; r < 32; r += 8)
        dst[(size_t)(bx + r) * 1024 + by + tx] = (bft)tile[tx][r];
}

// ---------- bf16 MFMA GEMM, 128x128 tile, BK=32, 4 waves, B^T ([N][K]) input ----------
// Staging via global_load_lds width=16 (m97 structure; LDS layout lane-linear so the
// wave-uniform-base + lane*16 constraint holds). Verified passing in rounds 5-7.
__global__ __launch_bounds__(256) void gemm_bt(
    const bft* __restrict__ A, const bft* __restrict__ Bt,
    const float* __restrict__ bias, const int* __restrict__ langs,
    int langStrideB, int langStrideBias,
    float* __restrict__ outF, bft* __restrict__ outB,
    int remapLog, int remapMul, int ldc)
{
    const int K = 1024;
    int tn = blockIdx.x, tm = blockIdx.y;
    int row0 = tm * 128, col0 = tn * 128;
    int lang = langs ? langs[row0 >> 8] : 0;   // 256 rows per batch elem; 128-tile never crosses b
    const bft* Ap = A + (size_t)row0 * K;
    const bft* Bp = Bt + (size_t)lang * langStrideB + (size_t)col0 * K;
    const float* biasp = bias + (size_t)lang * langStrideBias + col0;

    __shared__ bft As[128 * 32];
    __shared__ bft Bs[128 * 32];

    int t = threadIdx.x;
    int lane = t & 63, wave = t >> 6;
    int wm = wave & 1, wn = wave >> 1;
    int lrow = lane & 15, quad = lane >> 4;

    f32x4 acc[4][4] = {};

    for (int k0 = 0; k0 < K; k0 += 32) {
        __syncthreads();
#pragma unroll
        for (int c0 = 0; c0 < 512; c0 += 256) {    // 512 chunks of 16B, 2 per thread (A and B)
            int c = c0 + t;
            int r = c >> 2, co = (c & 3) << 3;
            __builtin_amdgcn_global_load_lds(
                (const __attribute__((address_space(1))) u32*)(Ap + (size_t)r * K + k0 + co),
                (__attribute__((address_space(3))) u32*)(As + c * 8), 16, 0, 0);
            __builtin_amdgcn_global_load_lds(
                (const __attribute__((address_space(1))) u32*)(Bp + (size_t)r * K + k0 + co),
                (__attribute__((address_space(3))) u32*)(Bs + c * 8), 16, 0, 0);
        }
        __syncthreads();
        bf16x8 af[4], bfr[4];
#pragma unroll
        for (int i = 0; i < 4; ++i)
            af[i] = *(const bf16x8*)(As + (wm * 64 + i * 16 + lrow) * 32 + quad * 8);
#pragma unroll
        for (int j = 0; j < 4; ++j)
            bfr[j] = *(const bf16x8*)(Bs + (wn * 64 + j * 16 + lrow) * 32 + quad * 8);
#pragma unroll
        for (int i = 0; i < 4; ++i)
#pragma unroll
            for (int j = 0; j < 4; ++j)
                acc[i][j] = __builtin_amdgcn_mfma_f32_16x16x32_bf16(af[i], bfr[j], acc[i][j], 0, 0, 0);
    }

#pragma unroll
    for (int i = 0; i < 4; ++i) {
#pragma unroll
        for (int j = 0; j < 4; ++j) {
#pragma unroll
            for (int r = 0; r < 4; ++r) {
                int m = wm * 64 + i * 16 + quad * 4 + r;   // C row = quad*4+reg
                int n = wn * 64 + j * 16 + lrow;           // C col = lane&15
                int grow = row0 + m;
                int orow = remapLog ? ((grow & ((1 << remapLog) - 1)) * remapMul + (grow >> remapLog))
                                    : grow;
                float v = acc[i][j][r] + biasp[n];
                size_t idx = (size_t)orow * ldc + col0 + n;
                if (outF) outF[idx] = v;
                else outB[idx] = (bft)v;
            }
        }
    }
}

// ---------- LayerNorm + ReLU per row, f32 in -> bf16 out ----------
__global__ __launch_bounds__(256) void ln_relu_kernel(
    const float* __restrict__ h1, bft* __restrict__ a2,
    const float* __restrict__ ln_g, const float* __restrict__ ln_b,
    const int* __restrict__ langs)
{
    int row = blockIdx.x;
    int lang = langs[row >> 8];
    const float* x = h1 + (size_t)row * 1024;
    int t = threadIdx.x;
    float4 v = ((const float4*)x)[t];
    float s = v.x + v.y + v.z + v.w;
    float ss = v.x * v.x + v.y * v.y + v.z * v.z + v.w * v.w;
#pragma unroll
    for (int off = 32; off > 0; off >>= 1) {
        s += __shfl_down(s, off, 64);
        ss += __shfl_down(ss, off, 64);
    }
    __shared__ float red[8];
    int wave = t >> 6, lane = t & 63;
    if (lane == 0) { red[wave] = s; red[4 + wave] = ss; }
    __syncthreads();
    float S = red[0] + red[1] + red[2] + red[3];
    float SS = red[4] + red[5] + red[6] + red[7];
    float mean = S * (1.f / 1024.f);
    float var = SS * (1.f / 1024.f) - mean * mean;   // population var (ddof=0)
    float inv = rsqrtf(var + LN_EPS);
    float4 g = ((const float4*)(ln_g + (size_t)lang * 1024))[t];
    float4 b = ((const float4*)(ln_b + (size_t)lang * 1024))[t];
    float y0 = fmaxf(0.f, (v.x - mean) * inv * g.x + b.x);
    float y1 = fmaxf(0.f, (v.y - mean) * inv * g.y + b.y);
    float y2 = fmaxf(0.f, (v.z - mean) * inv * g.z + b.z);
    float y3 = fmaxf(0.f, (v.w - mean) * inv * g.w + b.w);
    bf16x4 o = { (bft)y0, (bft)y1, (bft)y2, (bft)y3 };
    ((bf16x4*)(a2 + (size_t)row * 1024))[t] = o;
}

// ---------- BiLSTM recurrence (R0-proven, 760us) ----------
// 128 WGs (64/dir, 8 h-cols each). Flag protocol with MINIMAL LLC transactions:
//  - producers: coalesced plain sc0+sc1 (L1/L2-bypass -> LLC) dword stores of h,
//    per-thread vmcnt(0), barrier, then ONE atomicAdd per WG into a padded sub-counter.
//  - consumers: 8 poller lanes read 8 padded sub-counters (8 loads/WG/poll round),
//    then stage 32 KB h via 8 fully-coalesced global_load_dwordx4 sc0 sc1.
// hg: [dir(2)][parity(2)][32][256] u32 (bf16x2 entries). ctr: [dir][256][8 x 64B-padded].
// gin_*: [S][B][2048] bf16 (x@Wih.T + b, gate i,f,g,o). Whh_*: [2048][512] bf16.
// ys: [S][B][1024] bf16 (f|b), stored AFTER the counter bump (off critical path).
__global__ __launch_bounds__(256) void bilstm_kernel(
    const bft* __restrict__ gin_f, const bft* __restrict__ gin_b,
    const bft* __restrict__ Whh_f, const bft* __restrict__ Whh_b,
    const int* __restrict__ mask, bft* __restrict__ ys,
    u32* __restrict__ hg, u32* __restrict__ ctr)
{
    __shared__ u64 smem[8192];                 // 64 KB
    bft* Wlds = (bft*)smem;                    // [32][512] bf16, 16B-block XOR swizzle
    bft* hs   = (bft*)(smem + 4096);           // [32][512] bf16, same swizzle
    u32* hsd  = (u32*)(smem + 4096);           // dword view of hs for staging
    float* gatesF = (float*)(smem + 4096);     // [32][33] f32, aliases hs (used after S3)

    int blk = blockIdx.x;
    int dir = blk >> 6;                 // 0 = forward, 1 = backward
    int gslice = blk & 63;
    int jbase = gslice << 3;            // this WG owns h cols [jbase, jbase+8)
    const bft* Whh = dir ? Whh_b : Whh_f;
    const bft* gin = dir ? gin_b : gin_f;

    int t = threadIdx.x;
    int lane = t & 63, wave = t >> 6;
    int wm = wave & 1, wn = wave >> 1;
    int lrow = lane & 15, quad = lane >> 4;
    int am = t >> 2, jp = t & 3;        // activation phase: t<128, 2 cols each

    // preload Whh slice into LDS (swizzled): row r (gate=r/8, j=jbase+r%8)
    for (int i = 0; i < 8; ++i) {
        int c = t + i * 256;                       // 2048 chunks of 16B: r in [0,32), b64 in [0,64)
        int r = c >> 6, b64 = c & 63;
        int gate = r >> 3, jj = r & 7;
        int phys = b64 ^ (r & 7);
        ((uint4*)Wlds)[r * 64 + phys] =
            ((const uint4*)(Whh + (size_t)(gate * 512 + jbase + jj) * 512))[b64];
    }

    float cs0 = 0.f, cs1 = 0.f, hp0 = 0.f, hp1 = 0.f;  // cell/hidden state, 2 cols/thread
    u32* ysU = (u32*)ys;
    int mloS = t >> 6;                  // staging: within load i, row m = i*4 + (t>>6)
    int b16S = t & 63;                  // staging: 16B-block index within row

    for (int it = 0; it < 256; ++it) {
        int tt = dir ? (255 - it) : it;

        // ---- prefetch gin + mask for this step (independent of h) ----
        bf16x2 gpre[4];
        int mk = 0;
        if (t < 128) {
            size_t gb = ((size_t)tt * 32 + am) * 1024 + (jbase >> 1) + jp;
#pragma unroll
            for (int g = 0; g < 4; ++g)
                gpre[g] = ((const bf16x2*)gin)[gb + g * 256];
            mk = mask[am * 256 + tt];
        }

        // ---- wait + stage h_prev into LDS (swizzled) ----
        if (it == 0) {
#pragma unroll
            for (int i = 0; i < 16; ++i)
                smem[4096 + t + i * 256] = 0ull;
        } else {
            if (wave == 0) {
                const u32* cp = ctr + (size_t)(dir * 256 + it) * 128 + (lane < 8 ? lane * 16 : 0);
                for (;;) {
                    u32 c = 8u;
                    if (lane < 8)
                        c = __hip_atomic_load(cp, __ATOMIC_RELAXED, __HIP_MEMORY_SCOPE_AGENT);
                    if (__all(c >= 8u)) break;
                    __builtin_amdgcn_s_sleep(2);
                }
            }
            __syncthreads();                                       // S1
            const u32* hq = hg + (size_t)(dir * 2 + (it & 1)) * 8192;
            u32x4 r[8];
#pragma unroll
            for (int i = 0; i < 8; ++i)
                asm volatile("global_load_dwordx4 %0, %1, off sc0 sc1"
                             : "=v"(r[i]) : "v"(hq + i * 1024 + t * 4) : "memory");
            asm volatile("s_waitcnt vmcnt(0)" ::: "memory");
#pragma unroll
            for (int i = 0; i < 8; ++i) {
                int m = i * 4 + mloS;
                *(u32x4*)(hsd + m * 256 + ((b16S ^ (m & 7)) << 2)) = r[i];
            }
        }
        __syncthreads();                                           // S2

        // ---- gates_hh = h_prev @ Whh_slice^T : [32x512] @ [512x32] ----
        f32x4 acc0 = {}, acc1 = {};
        int arow = wm * 16 + lrow, brow = wn * 16 + lrow;
#pragma unroll
        for (int kk = 0; kk < 16; ++kk) {
            int b16 = kk * 4 + quad;
            bf16x8 a = *(const bf16x8*)(hs   + arow * 512 + ((b16 ^ (arow & 7)) << 3));
            bf16x8 b = *(const bf16x8*)(Wlds + brow * 512 + ((b16 ^ (brow & 7)) << 3));
            if (kk & 1) acc1 = __builtin_amdgcn_mfma_f32_16x16x32_bf16(a, b, acc1, 0, 0, 0);
            else        acc0 = __builtin_amdgcn_mfma_f32_16x16x32_bf16(a, b, acc0, 0, 0, 0);
        }
        f32x4 acc = acc0 + acc1;
        __syncthreads();                                           // S3 (hs dead; gates may alias)

#pragma unroll
        for (int r = 0; r < 4; ++r)
            gatesF[(wm * 16 + quad * 4 + r) * 33 + wn * 16 + lrow] = acc[r];
        __syncthreads();                                           // S4

        // ---- activation: threads 0..127, 2 cells each ----
        u32 ypack = 0;
        if (t < 128) {
            int l0 = 2 * jp;
            const float* gr = gatesF + am * 33;
            float xi0 = gr[l0]      + (float)gpre[0][0], xi1 = gr[l0 + 1]      + (float)gpre[0][1];
            float xf0 = gr[8 + l0]  + (float)gpre[1][0], xf1 = gr[8 + l0 + 1]  + (float)gpre[1][1];
            float xg0 = gr[16 + l0] + (float)gpre[2][0], xg1 = gr[16 + l0 + 1] + (float)gpre[2][1];
            float xo0 = gr[24 + l0] + (float)gpre[3][0], xo1 = gr[24 + l0 + 1] + (float)gpre[3][1];
            float cn0 = sigmoidf_(xf0) * cs0 + sigmoidf_(xi0) * tanhf_(xg0);
            float cn1 = sigmoidf_(xf1) * cs1 + sigmoidf_(xi1) * tanhf_(xg1);
            float hn0 = sigmoidf_(xo0) * tanhf_(cn0);
            float hn1 = sigmoidf_(xo1) * tanhf_(cn1);
            union { bf16x2 v; u32 u; } hpk, ypk;
            if (mk) {
                cs0 = cn0; cs1 = cn1; hp0 = hn0; hp1 = hn1;
                hpk.v = bf16x2{ (bft)hn0, (bft)hn1 };
                ypk.u = hpk.u;
            } else {
                hpk.v = bf16x2{ (bft)hp0, (bft)hp1 };
                ypk.u = 0u;
            }
            ypack = ypk.u;
            // h store: plain coalescing store, L1/L2-bypass -> LLC
            u32* ha = hg + (size_t)(dir * 2 + ((it + 1) & 1)) * 8192 + am * 256 + gslice * 4 + jp;
            u32 hv = hpk.u;
            asm volatile("global_store_dword %0, %1, off sc0 sc1" :: "v"(ha), "v"(hv) : "memory");
        }
        asm volatile("s_waitcnt vmcnt(0)" ::: "memory");           // own stores acked at LLC
        __syncthreads();                                           // S5
        if (t == 0 && it < 255)
            __hip_atomic_fetch_add(ctr + (size_t)(dir * 256 + it + 1) * 128 + (gslice & 7) * 16,
                                   1u, __ATOMIC_RELAXED, __HIP_MEMORY_SCOPE_AGENT);
        // ys store AFTER the signal — off the critical path
        if (t < 128)
            ysU[((size_t)tt * 32 + am) * 512 + dir * 256 + gslice * 4 + jp] = ypack;
    }
}

// ---------- host launcher ----------
extern "C" void kernel_launch(void* const* d_in, const int* in_sizes, int n_in,
                              void* d_out, int out_size, void* d_ws, size_t ws_size,
                              hipStream_t stream)
{
    const float* X     = (const float*)d_in[0];   // [32,256,1024]
    const int*   amask = (const int*)d_in[1];     // [32,256]
    const int*   langs = (const int*)d_in[2];     // [32]
    const float* W1    = (const float*)d_in[3];   // [5,1024,1024] (K-major)
    const float* b1    = (const float*)d_in[4];   // [5,1024]
    const float* ln_g  = (const float*)d_in[5];
    const float* ln_b  = (const float*)d_in[6];
    const float* W2    = (const float*)d_in[7];
    const float* b2    = (const float*)d_in[8];
    const float* Wih_f = (const float*)d_in[9];   // [2048,1024] = [N][K]
    const float* Whh_f = (const float*)d_in[10];  // [2048,512]
    const float* b_f   = (const float*)d_in[11];  // [2048]
    const float* Wih_b = (const float*)d_in[12];
    const float* Whh_b = (const float*)d_in[13];
    const float* b_b   = (const float*)d_in[14];
    const float* Wp    = (const float*)d_in[15];  // [256,1024] = [N][K]
    const float* bp    = (const float*)d_in[16];
    float* out = (float*)d_out;

    char* ws = (char*)d_ws;
    size_t off = 0;
    auto alloc = [&](size_t bytes) -> void* {
        void* p = ws + off;
        off += (bytes + 255) & ~(size_t)255;
        return p;
    };
    bft* Xbf   = (bft*)alloc(8192ull * 1024 * 2);
    bft* W1t   = (bft*)alloc(5ull * 1024 * 1024 * 2);
    bft* W2t   = (bft*)alloc(5ull * 1024 * 1024 * 2);
    bft* Wihf  = (bft*)alloc(2048ull * 1024 * 2);
    bft* Wihb  = (bft*)alloc(2048ull * 1024 * 2);
    bft* Whhf  = (bft*)alloc(2048ull * 512 * 2);
    bft* Whhb  = (bft*)alloc(2048ull * 512 * 2);
    bft* Wpb   = (bft*)alloc(256ull * 1024 * 2);
    float* h1  = (float*)alloc(8192ull * 1024 * 4);
    bft* a2    = (bft*)alloc(8192ull * 1024 * 2);
    bft* adapt = (bft*)alloc(8192ull * 1024 * 2);
    bft* ginf  = (bft*)alloc(256ull * 32 * 2048 * 2);
    bft* ginb  = (bft*)alloc(256ull * 32 * 2048 * 2);
    bft* ysb   = (bft*)alloc(256ull * 32 * 1024 * 2);
    u32* hg    = (u32*)alloc(2ull * 2 * 32 * 256 * 4);   // h entries (bf16x2), 256 KB
    u32* ctr   = (u32*)alloc(2ull * 256 * 8 * 16 * 4);   // padded step counters, 256 KB
    (void)ws_size; (void)in_sizes; (void)n_in; (void)out_size;

    auto cvt = [&](const float* src, bft* dst, int n) {
        int n4 = n >> 2;
        hipLaunchKernelGGL(cvt_f32_bf16, dim3((n4 + 255) / 256), dim3(256), 0, stream, src, dst, n4);
    };
    cvt(X, Xbf, 8192 * 1024);
    cvt(Wih_f, Wihf, 2048 * 1024);
    cvt(Wih_b, Wihb, 2048 * 1024);
    cvt(Whh_f, Whhf, 2048 * 512);
    cvt(Whh_b, Whhb, 2048 * 512);
    cvt(Wp, Wpb, 256 * 1024);
    hipLaunchKernelGGL(zero_u32, dim3(256), dim3(256), 0, stream, ctr, 65536);
    hipLaunchKernelGGL(transpose_cvt_w, dim3(32, 32, 10), dim3(256), 0, stream, W1, W2, W1t, W2t);

    // Adapter GEMM1: h1 = X @ W1[lang] + b1[lang]   (f32 out for LN)
    hipLaunchKernelGGL(gemm_bt, dim3(8, 64), dim3(256), 0, stream,
        Xbf, W1t, b1, langs, 1024 * 1024, 1024, h1, (bft*)nullptr, 0, 0, 1024);
    // LN + ReLU -> a2 (bf16)
    hipLaunchKernelGGL(ln_relu_kernel, dim3(8192), dim3(256), 0, stream, h1, a2, ln_g, ln_b, langs);
    // Adapter GEMM2: adapt = a2 @ W2[lang] + b2[lang]   (bf16 out)
    hipLaunchKernelGGL(gemm_bt, dim3(8, 64), dim3(256), 0, stream,
        a2, W2t, b2, langs, 1024 * 1024, 1024, (float*)nullptr, adapt, 0, 0, 1024);
    // Input gates: gin = adapt @ Wih^T + b, remap row (b*256+s) -> (s*32+b), ldc 2048
    hipLaunchKernelGGL(gemm_bt, dim3(16, 64), dim3(256), 0, stream,
        adapt, Wihf, b_f, (const int*)nullptr, 0, 0, (float*)nullptr, ginf, 8, 32, 2048);
    hipLaunchKernelGGL(gemm_bt, dim3(16, 64), dim3(256), 0, stream,
        adapt, Wihb, b_b, (const int*)nullptr, 0, 0, (float*)nullptr, ginb, 8, 32, 2048);
    // Recurrence (cooperative launch guarantees co-residency for the spin-wait)
    {
        void* args[] = { (void*)&ginf, (void*)&ginb, (void*)&Whhf, (void*)&Whhb,
                         (void*)&amask, (void*)&ysb, (void*)&hg, (void*)&ctr };
        hipLaunchCooperativeKernel((const void*)bilstm_kernel, dim3(128), dim3(256), args, 0, stream);
    }
    // Projection: out = ys @ Wp^T + bp, remap row (s*32+b) -> (b*256+s), ldc 256
    hipLaunchKernelGGL(gemm_bt, dim3(2, 64), dim3(256), 0, stream,
        ysb, Wpb, bp, (const int*)nullptr, 0, 0, out, (bft*)nullptr, 5, 256, 256);
}